// Round 5
// baseline (569.274 us; speedup 1.0000x reference)
//
#include <hip/hip_runtime.h>
#include <hip/hip_fp16.h>
#include <type_traits>

static const long long N_ = 50000;
static const long long E_ = 800000;
#define LOG2E 1.44269504088896f

typedef __attribute__((ext_vector_type(8))) short bf16x8;
typedef __attribute__((ext_vector_type(4))) float f32x4;

__device__ __forceinline__ float lrelu(float x){ return x >= 0.f ? x : 0.2f*x; }
__device__ __forceinline__ unsigned fkey(float x){
  unsigned u = __float_as_uint(x);
  return (u & 0x80000000u) ? ~u : (u | 0x80000000u);
}
__device__ __forceinline__ float unfkey(unsigned k){
  return __uint_as_float((k & 0x80000000u) ? (k & 0x7fffffffu) : ~k);
}
__device__ __forceinline__ unsigned h2u(__half2 h){ return *(unsigned*)&h; }

// ---- fused prologue: deg histogram + ea column sums + W1 bf16-split prep ----
__global__ void k_pre(const int* __restrict__ ei, int* __restrict__ deg,
                      const float* __restrict__ ea, float* __restrict__ sum_ea,
                      const float* __restrict__ W1, ushort* __restrict__ Bhi,
                      ushort* __restrict__ Blo){
  int t = threadIdx.x;
  long long e = (long long)blockIdx.x*256 + t;
  if (e < E_) atomicAdd(&deg[ei[E_ + e]], 1);
  if (blockIdx.x < 256){
    int k = blockIdx.x, n = t;
    float v = W1[k*256+n];
    unsigned u = __float_as_uint(v);
    ushort hi = (ushort)(u>>16);
    float rem = v - __uint_as_float(u & 0xffff0000u);
    unsigned ur = __float_as_uint(rem);
    ushort lo = (ushort)((ur + 0x7fff + ((ur>>16)&1)) >> 16);
    int tl = n>>4, kb = k>>5, q = (k>>3)&3, j = k&7;
    long long idx = ((((long long)tl*8+kb)*64 + q*16 + (n&15))<<3) + j;
    Bhi[idx] = hi; Blo[idx] = lo;
  }
  __shared__ float lds[256];
  float s = 0.f;
  for (long long i = (long long)blockIdx.x*256 + t; i < E_*4; i += (long long)gridDim.x*256)
    s += ea[i];
  lds[t] = s; __syncthreads();
  for (int st=128; st>=4; st>>=1){ if (t<st) lds[t] += lds[t+st]; __syncthreads(); }
  if (t<4) atomicAdd(&sum_ea[t], lds[t]);
}

// ---- parallel scan, phase 1: per-block sums of deg ----
__global__ void k_scan1(const int* __restrict__ deg, int* __restrict__ bsum){
  __shared__ int lds[256];
  int t = threadIdx.x;
  long long idx = (long long)blockIdx.x*256 + t;
  lds[t] = (idx < N_) ? deg[idx] : 0;
  __syncthreads();
  for (int st=128; st>=1; st>>=1){ if (t<st) lds[t] += lds[t+st]; __syncthreads(); }
  if (t==0) bsum[blockIdx.x] = lds[0];
}

// ---- phase 2: scan block sums + fused "small" precompute (log2-scaled) ----
// small layout: [0..15]=Ae0*log2e, [16..31]=Ae1*log2e, [32..35]=loop0, [36..39]=loop1
__global__ void k_scan2(const int* __restrict__ bsum, int* __restrict__ bpre, int nb,
                        int* __restrict__ rowptr,
                        const float* __restrict__ We0, const float* __restrict__ ae0,
                        const float* __restrict__ We1, const float* __restrict__ ae1,
                        const float* __restrict__ sum_ea, float* __restrict__ small){
  __shared__ int lds[256];
  int t = threadIdx.x;
  int v = (t < nb) ? bsum[t] : 0;
  lds[t] = v; __syncthreads();
  for (int off=1; off<256; off<<=1){
    int add = (t>=off) ? lds[t-off] : 0;
    __syncthreads();
    lds[t] += add;
    __syncthreads();
  }
  if (t < nb) bpre[t] = lds[t] - v;     // exclusive
  if (t == 0) rowptr[N_] = (int)E_;
  if (t < 32){
    int l = t>>4, f = (t>>2)&3, h = t&3;
    const float* We = l ? We1 : We0;
    const float* ae = l ? ae1 : ae0;
    float s = 0.f;
    for (int cc=0; cc<64; cc++) s += We[f*256 + h*64 + cc]*ae[h*64+cc];
    small[l*16 + f*4 + h] = s * LOG2E;
  }
  __syncthreads();
  if (t < 8){
    int l = t>>2, h = t&3;
    const float* Ae = small + l*16;       // already scaled
    const float invE = 1.f/(float)E_;
    float s = 0.f;
    for (int f=0; f<4; f++) s += sum_ea[f]*invE*Ae[f*4+h];
    small[32 + l*4 + h] = s;
  }
}

// ---- phase 3: local scan + block offset -> rowptr/cursor ----
__global__ void k_scan3(const int* __restrict__ deg, const int* __restrict__ bpre,
                        int* __restrict__ rowptr, int* __restrict__ cursor){
  __shared__ int lds[256];
  int t = threadIdx.x;
  long long idx = (long long)blockIdx.x*256 + t;
  int v = (idx < N_) ? deg[idx] : 0;
  lds[t] = v; __syncthreads();
  for (int off=1; off<256; off<<=1){
    int add = (t>=off) ? lds[t-off] : 0;
    __syncthreads();
    lds[t] += add;
    __syncthreads();
  }
  if (idx < N_){
    int rp = bpre[blockIdx.x] + lds[t] - v;
    rowptr[idx] = rp; cursor[idx] = rp;
  }
}

// ---- h0 = x @ W0 (K=5), stored fp16; als0/ald0 (log2-scaled) ----
__global__ void k_h0(const float* __restrict__ x, const float* __restrict__ W0,
                     const float* __restrict__ as0, const float* __restrict__ ad0,
                     __half* __restrict__ h0, float* __restrict__ als, float* __restrict__ ald){
  int wid = (int)(((long long)blockIdx.x*blockDim.x + threadIdx.x) >> 6);
  int lane = threadIdx.x & 63;
  if (wid >= (int)N_) return;
  const float* xr = x + wid*5;
  float xv[5];
  #pragma unroll
  for (int f=0; f<5; f++) xv[f] = xr[f];
  int c = lane*4;
  float a0=0,a1=0,a2=0,a3=0;
  #pragma unroll
  for (int f=0; f<5; f++){
    const float* wr = W0 + f*256 + c;
    a0 += xv[f]*wr[0]; a1 += xv[f]*wr[1]; a2 += xv[f]*wr[2]; a3 += xv[f]*wr[3];
  }
  uint2 pk = make_uint2(h2u(__floats2half2_rn(a0,a1)), h2u(__floats2half2_rn(a2,a3)));
  *(uint2*)(h0 + wid*256 + c) = pk;
  const float* asp = as0 + c;
  const float* adp = ad0 + c;
  float ss = a0*asp[0]+a1*asp[1]+a2*asp[2]+a3*asp[3];
  float dd = a0*adp[0]+a1*adp[1]+a2*adp[2]+a3*adp[3];
  int head = lane>>4;
  #pragma unroll
  for (int m=1; m<16; m<<=1){ ss += __shfl_xor(ss, m); dd += __shfl_xor(dd, m); }
  if ((lane&15)==0){ als[wid*4+head]=ss*LOG2E; ald[wid*4+head]=dd*LOG2E; }
}

// ---- scatter edges into CSR; fused layer-0 p = exp2(lrelu(alpha)); ale1 fp16 ----
__global__ void k_scatter(const int* __restrict__ ei, const float* __restrict__ ea,
                          int* __restrict__ cursor, int* __restrict__ csr_src,
                          int* __restrict__ csr_dst,
                          __half* __restrict__ ale1h, __half* __restrict__ p0h,
                          const float* __restrict__ small,
                          const float* __restrict__ als0, const float* __restrict__ ald0){
  long long e = (long long)blockIdx.x*256 + threadIdx.x;
  if (e >= E_) return;
  int s = ei[e], d = ei[E_+e];
  int pos = atomicAdd(&cursor[d], 1);
  csr_src[pos] = s;
  csr_dst[pos] = d;
  float4 v = *(const float4*)(ea + e*4);
  float4 As = *(const float4*)(als0 + s*4);
  float4 Ad = *(const float4*)(ald0 + d*4);
  float as_[4] = {As.x,As.y,As.z,As.w};
  float ad_[4] = {Ad.x,Ad.y,Ad.z,Ad.w};
  float p0[4], o1[4];
  #pragma unroll
  for (int h=0; h<4; h++){
    float a0 = v.x*small[0+h]  + v.y*small[4+h]  + v.z*small[8+h]  + v.w*small[12+h];
    p0[h] = exp2f(lrelu(as_[h] + ad_[h] + a0));
    o1[h] = v.x*small[16+h] + v.y*small[20+h] + v.z*small[24+h] + v.w*small[28+h];
  }
  uint2 pkp = make_uint2(h2u(__floats2half2_rn(p0[0],p0[1])), h2u(__floats2half2_rn(p0[2],p0[3])));
  uint2 pke = make_uint2(h2u(__floats2half2_rn(o1[0],o1[1])), h2u(__floats2half2_rn(o1[2],o1[3])));
  *(uint2*)(p0h + (long long)pos*4) = pkp;
  *(uint2*)(ale1h + (long long)pos*4) = pke;
}

// ---- layer-1 p: edge-parallel exp2(lrelu(als1[s]+ald1[d]+ale1)) ----
__global__ void k_palpha1(const int* __restrict__ csr_src, const int* __restrict__ csr_dst,
                          const __half* __restrict__ ale1h,
                          const float* __restrict__ als1, const float* __restrict__ ald1,
                          __half* __restrict__ p1h){
  long long i = (long long)blockIdx.x*256 + threadIdx.x;
  if (i >= E_) return;
  int s = csr_src[i], d = csr_dst[i];
  float4 As = *(const float4*)(als1 + s*4);
  float4 Ad = *(const float4*)(ald1 + d*4);
  uint2 pke = *(const uint2*)(ale1h + i*4);
  float2 e01 = __half22float2(*(__half2*)&pke.x);
  float2 e23 = __half22float2(*(__half2*)&pke.y);
  float p0 = exp2f(lrelu(As.x+Ad.x+e01.x));
  float p1 = exp2f(lrelu(As.y+Ad.y+e01.y));
  float p2 = exp2f(lrelu(As.z+Ad.z+e23.x));
  float p3 = exp2f(lrelu(As.w+Ad.w+e23.y));
  uint2 pk = make_uint2(h2u(__floats2half2_rn(p0,p1)), h2u(__floats2half2_rn(p2,p3)));
  *(uint2*)(p1h + i*4) = pk;
}

// ---- GAT aggregation: one wave/node; precomputed p; 8-wide independent gathers ----
template<typename OutT, bool RELU>
__global__ __launch_bounds__(256) void k_agg(const __half* __restrict__ hin,
    const float* __restrict__ als, const float* __restrict__ ald,
    const int* __restrict__ rowptr, const int* __restrict__ csr_src,
    const __half* __restrict__ ph,
    const float* __restrict__ small, int loop_off,
    const float* __restrict__ bias, OutT* __restrict__ out){
  int wid = (int)(((long long)blockIdx.x*256 + threadIdx.x) >> 6);
  int lane = threadIdx.x & 63;
  if (wid >= (int)N_) return;
  int head = lane>>4, c = lane*4;
  const uint2* hp = (const uint2*)hin;
  // self-loop
  float aS = lrelu(als[wid*4+head] + ald[wid*4+head] + small[loop_off+head]);
  float pS = exp2f(aS);
  uint2 r0 = hp[wid*64 + lane];
  float2 f01 = __half22float2(*(__half2*)&r0.x);
  float2 f23 = __half22float2(*(__half2*)&r0.y);
  float den = pS;
  float ax = pS*f01.x, ay = pS*f01.y, az = pS*f23.x, aw = pS*f23.y;
  int beg = rowptr[wid], end = rowptr[wid+1];
  int i = beg;
  for (; i+7 < end; i += 8){
    int   sidx[8]; float pv[8]; uint2 rr[8];
    #pragma unroll
    for (int k=0;k<8;k++) sidx[k] = csr_src[i+k];
    #pragma unroll
    for (int k=0;k<8;k++) pv[k] = __half2float(ph[(i+k)*4+head]);
    #pragma unroll
    for (int k=0;k<8;k++) rr[k] = hp[sidx[k]*64+lane];
    #pragma unroll
    for (int k=0;k<8;k++){
      float2 u01 = __half22float2(*(__half2*)&rr[k].x);
      float2 u23 = __half22float2(*(__half2*)&rr[k].y);
      den += pv[k];
      ax += pv[k]*u01.x; ay += pv[k]*u01.y;
      az += pv[k]*u23.x; aw += pv[k]*u23.y;
    }
  }
  for (; i < end; i++){
    int s0 = csr_src[i];
    float p = __half2float(ph[i*4+head]);
    uint2 r = hp[s0*64+lane];
    float2 u01 = __half22float2(*(__half2*)&r.x);
    float2 u23 = __half22float2(*(__half2*)&r.y);
    den += p;
    ax += p*u01.x; ay += p*u01.y; az += p*u23.x; aw += p*u23.y;
  }
  float inv = 1.f/(den + 1e-16f);
  const float* bp = bias + c;
  float ox = ax*inv + bp[0], oy = ay*inv + bp[1];
  float oz = az*inv + bp[2], ow = aw*inv + bp[3];
  if (RELU){ ox=fmaxf(ox,0.f); oy=fmaxf(oy,0.f); oz=fmaxf(oz,0.f); ow=fmaxf(ow,0.f); }
  if constexpr (std::is_same<OutT,__half>::value){
    uint2 qk = make_uint2(h2u(__floats2half2_rn(ox,oy)), h2u(__floats2half2_rn(oz,ow)));
    *(uint2*)(out + wid*256 + c) = qk;
  } else {
    *(float4*)(out + wid*256 + c) = make_float4(ox,oy,oz,ow);
  }
}

// ---- h1 = x1 @ W1 via split-bf16 MFMA (3 products); fp16 out; fused als1/ald1 ----
__global__ __launch_bounds__(256) void k_gemm(const float* __restrict__ A,
    const ushort* __restrict__ Bhi, const ushort* __restrict__ Blo,
    __half* __restrict__ Ch, const float* __restrict__ as1, const float* __restrict__ ad1,
    float* __restrict__ als, float* __restrict__ ald){
  __shared__ ushort Ah[32*264];
  __shared__ ushort Al[32*264];
  int t = threadIdx.x;
  long long base = (long long)blockIdx.x*32;
  for (int i=t; i<2048; i+=256){
    int r = i>>6, q4 = i&63;
    float4 v = make_float4(0.f,0.f,0.f,0.f);
    if (base + r < N_) v = *(const float4*)(A + (base+r)*256 + q4*4);
    float vv[4] = {v.x,v.y,v.z,v.w};
    ushort hh[4], ll[4];
    #pragma unroll
    for (int e=0;e<4;e++){
      unsigned u = __float_as_uint(vv[e]);
      hh[e] = (ushort)(u>>16);
      float rem = vv[e] - __uint_as_float(u & 0xffff0000u);
      unsigned ur = __float_as_uint(rem);
      ll[e] = (ushort)((ur + 0x7fff + ((ur>>16)&1)) >> 16);
    }
    int off = r*264 + q4*4;
    *(ushort4*)(Ah+off) = make_ushort4(hh[0],hh[1],hh[2],hh[3]);
    *(ushort4*)(Al+off) = make_ushort4(ll[0],ll[1],ll[2],ll[3]);
  }
  __syncthreads();
  int w = t>>6, lane = t&63, m = lane&15, q = lane>>4;
  int rbase = (w>>1)*16;
  int nhalf = (w&1)*8;
  f32x4 acc[8];
  #pragma unroll
  for (int i=0;i<8;i++) acc[i] = (f32x4){0.f,0.f,0.f,0.f};
  for (int kb=0; kb<8; kb++){
    int aoff = (rbase+m)*264 + kb*32 + q*8;
    bf16x8 ah = *(const bf16x8*)(Ah + aoff);
    bf16x8 al = *(const bf16x8*)(Al + aoff);
    #pragma unroll
    for (int tt=0; tt<8; tt++){
      long long bidx = ((((long long)(nhalf+tt)*8+kb)*64 + lane)<<3);
      bf16x8 bh = *(const bf16x8*)(Bhi + bidx);
      bf16x8 bl = *(const bf16x8*)(Blo + bidx);
      acc[tt] = __builtin_amdgcn_mfma_f32_16x16x32_bf16(ah, bh, acc[tt], 0,0,0);
      acc[tt] = __builtin_amdgcn_mfma_f32_16x16x32_bf16(al, bh, acc[tt], 0,0,0);
      acc[tt] = __builtin_amdgcn_mfma_f32_16x16x32_bf16(ah, bl, acc[tt], 0,0,0);
    }
  }
  float ssv[4][2], ddv[4][2];
  #pragma unroll
  for (int r=0;r<4;r++){ ssv[r][0]=0.f; ssv[r][1]=0.f; ddv[r][0]=0.f; ddv[r][1]=0.f; }
  #pragma unroll
  for (int tt=0; tt<8; tt++){
    int col = (nhalf+tt)*16 + m;
    float as_ = as1[col], ad_ = ad1[col];
    int hh = tt>>2;
    #pragma unroll
    for (int r=0;r<4;r++){
      ssv[r][hh] += acc[tt][r]*as_;
      ddv[r][hh] += acc[tt][r]*ad_;
    }
  }
  #pragma unroll
  for (int r=0;r<4;r++){
    #pragma unroll
    for (int hh=0; hh<2; hh++){
      #pragma unroll
      for (int mm=1; mm<16; mm<<=1){
        ssv[r][hh] += __shfl_xor(ssv[r][hh], mm);
        ddv[r][hh] += __shfl_xor(ddv[r][hh], mm);
      }
    }
  }
  #pragma unroll
  for (int r=0;r<4;r++){
    long long grow = base + rbase + q*4 + r;
    if (grow < N_){
      #pragma unroll
      for (int tt=0; tt<8; tt++)
        Ch[grow*256 + (nhalf+tt)*16 + m] = __float2half(acc[tt][r]);
      if (m==0){
        int hb = (w&1)*2;
        als[grow*4 + hb+0] = ssv[r][0]*LOG2E;
        ald[grow*4 + hb+0] = ddv[r][0]*LOG2E;
        als[grow*4 + hb+1] = ssv[r][1]*LOG2E;
        ald[grow*4 + hb+1] = ddv[r][1]*LOG2E;
      }
    }
  }
}

// ---- column-wise sum & max over nodes (fp16 h2) ----
__global__ void k_pool1(const __half* __restrict__ h2, float* __restrict__ sum_pool,
                        unsigned* __restrict__ maxkey){
  int c = threadIdx.x; // 256
  float s = 0.f; float m = -3.4e38f;
  for (long long n = blockIdx.x; n < N_; n += gridDim.x){
    float v = __half2float(h2[n*256+c]); s += v; m = fmaxf(m, v);
  }
  atomicAdd(&sum_pool[c], s);
  atomicMax(&maxkey[c], fkey(m));
}

// ---- s[n] = dot(h2[n], mean_pool); accumulate sum(exp(s)) directly ----
__global__ void k_atts(const __half* __restrict__ h2, const float* __restrict__ sum_pool,
                       float* __restrict__ sarr, float* __restrict__ ssum){
  __shared__ float lsum[4];
  int t = threadIdx.x; int lane = t&63; int w = t>>6;
  const float invN = 1.f/(float)N_;
  int c = lane*4;
  float4 mp = *(const float4*)(sum_pool + c);
  float esum = 0.f;
  for (long long wid = (long long)blockIdx.x*4 + w; wid < N_; wid += (long long)gridDim.x*4){
    uint2 pk = *(const uint2*)(h2 + wid*256 + c);
    float2 a01 = __half22float2(*(__half2*)&pk.x);
    float2 a23 = __half22float2(*(__half2*)&pk.y);
    float s = (a01.x*mp.x + a01.y*mp.y + a23.x*mp.z + a23.y*mp.w)*invN;
    #pragma unroll
    for (int m=1; m<64; m<<=1) s += __shfl_xor(s, m);
    if (lane==0){ sarr[wid] = s; esum += __expf(s); }
  }
  if (lane==0) lsum[w] = esum;
  __syncthreads();
  if (t==0) atomicAdd(ssum, lsum[0]+lsum[1]+lsum[2]+lsum[3]);
}

// ---- att_pool[c] = sum_n h2[n][c]*exp(s[n])/ssum ----
__global__ void k_attp(const __half* __restrict__ h2, const float* __restrict__ sarr,
                       const float* __restrict__ ssum, float* __restrict__ att_pool){
  int c = threadIdx.x; // 256
  float inv = 1.f/(*ssum);
  float acc = 0.f;
  for (long long n = blockIdx.x; n < N_; n += gridDim.x){
    float w = __expf(sarr[n])*inv;
    acc += __half2float(h2[n*256+c])*w;
  }
  atomicAdd(&att_pool[c], acc);
}

// ---- final MLP: [768] -> 128 -> 64 -> 128, split-K across 512 threads ----
__global__ void k_mlp(const float* __restrict__ sum_pool, const unsigned* __restrict__ maxkey,
                      const float* __restrict__ att_pool,
                      const float* __restrict__ Wm1, const float* __restrict__ bm1,
                      const float* __restrict__ Wm2, const float* __restrict__ bm2,
                      const float* __restrict__ Wm3, const float* __restrict__ bm3,
                      float* __restrict__ out){
  __shared__ float comb[768];
  __shared__ float z1p[4][128]; __shared__ float z1[128];
  __shared__ float z2p[8][64];  __shared__ float z2[64];
  __shared__ float z3p[4][128];
  int t = threadIdx.x; // 512
  const float invN = 1.f/(float)N_;
  for (int i=t; i<768; i+=512){
    float v;
    if (i < 256)      v = sum_pool[i]*invN;
    else if (i < 512) v = unfkey(maxkey[i-256]);
    else              v = att_pool[i-512];
    comb[i] = v;
  }
  __syncthreads();
  { int n = t&127, part = t>>7;
    float a = 0.f;
    for (int f=part*192; f<part*192+192; f++) a += comb[f]*Wm1[f*128+n];
    z1p[part][n] = a;
  }
  __syncthreads();
  if (t < 128)
    z1[t] = fmaxf(bm1[t] + z1p[0][t]+z1p[1][t]+z1p[2][t]+z1p[3][t], 0.f);
  __syncthreads();
  { int n = t&63, part = t>>6;
    float a = 0.f;
    for (int f=part*16; f<part*16+16; f++) a += z1[f]*Wm2[f*64+n];
    z2p[part][n] = a;
  }
  __syncthreads();
  if (t < 64){
    float a = bm2[t];
    #pragma unroll
    for (int p=0;p<8;p++) a += z2p[p][t];
    z2[t] = fmaxf(a, 0.f);
  }
  __syncthreads();
  { int n = t&127, part = t>>7;
    float a = 0.f;
    for (int f=part*16; f<part*16+16; f++) a += z2[f]*Wm3[f*128+n];
    z3p[part][n] = a;
  }
  __syncthreads();
  if (t < 128)
    out[t] = bm3[t] + z3p[0][t]+z3p[1][t]+z3p[2][t]+z3p[3][t];
}

extern "C" void kernel_launch(void* const* d_in, const int* in_sizes, int n_in,
                              void* d_out, int out_size, void* d_ws, size_t ws_size,
                              hipStream_t stream){
  (void)in_sizes; (void)n_in; (void)out_size; (void)ws_size;
  const float* x   = (const float*)d_in[0];
  const int*   ei  = (const int*)d_in[1];
  const float* ea  = (const float*)d_in[2];
  const float* W0  = (const float*)d_in[3];
  const float* as0 = (const float*)d_in[4];
  const float* ad0 = (const float*)d_in[5];
  const float* We0 = (const float*)d_in[6];
  const float* ae0 = (const float*)d_in[7];
  const float* b0  = (const float*)d_in[8];
  const float* W1  = (const float*)d_in[9];
  const float* as1 = (const float*)d_in[10];
  const float* ad1 = (const float*)d_in[11];
  const float* We1 = (const float*)d_in[12];
  const float* ae1 = (const float*)d_in[13];
  const float* b1  = (const float*)d_in[14];
  const float* Wm1 = (const float*)d_in[15];
  const float* bm1 = (const float*)d_in[16];
  const float* Wm2 = (const float*)d_in[17];
  const float* bm2 = (const float*)d_in[18];
  const float* Wm3 = (const float*)d_in[19];
  const float* bm3 = (const float*)d_in[20];
  float* out = (float*)d_out;

  char* ws = (char*)d_ws;
  size_t o = 0;
  auto alloc = [&](size_t bytes)->size_t{
    size_t r = o; o = (o + bytes + 255) & ~(size_t)255; return r;
  };
  size_t o_bufF   = alloc((size_t)N_*256*4);   // x1 (fp32), then h2 (fp16)
  size_t o_bufH   = alloc((size_t)N_*256*2);   // h0, then h1 (fp16)
  size_t o_als0   = alloc((size_t)N_*4*4);
  size_t o_ald0   = alloc((size_t)N_*4*4);
  size_t o_als1   = alloc((size_t)N_*4*4);
  size_t o_ald1   = alloc((size_t)N_*4*4);
  size_t o_rowptr = alloc((size_t)(N_+1)*4);
  size_t o_cursor = alloc((size_t)N_*4);
  size_t o_csrsrc = alloc((size_t)E_*4);
  size_t o_csrdst = alloc((size_t)E_*4);
  size_t o_ale1   = alloc((size_t)E_*4*2);     // fp16 x4 per edge (layer-1 al_e)
  size_t o_p0     = alloc((size_t)E_*4*2);     // fp16 x4 per edge (layer-0 p)
  size_t o_p1     = alloc((size_t)E_*4*2);     // fp16 x4 per edge (layer-1 p)
  size_t o_sarr   = alloc((size_t)N_*4);
  size_t o_Bhi    = alloc((size_t)256*256*2);
  size_t o_Blo    = alloc((size_t)256*256*2);
  size_t o_bsum   = alloc(256*4);
  size_t o_bpre   = alloc(256*4);
  // --- zero block ---
  size_t zstart   = o;
  size_t o_deg    = alloc((size_t)N_*4);
  size_t o_sumea  = alloc(16);
  size_t o_sumpool= alloc(256*4);
  size_t o_maxkey = alloc(256*4);
  size_t o_attpool= alloc(256*4);
  size_t o_ssum   = alloc(4);
  size_t zend     = o;
  size_t o_small  = alloc(40*4);

  float*  bufF   = (float*)(ws + o_bufF);
  __half* bufH   = (__half*)(ws + o_bufH);
  __half* h2h    = (__half*)(ws + o_bufF);     // reuse bufF region for fp16 h2
  float* pals0  = (float*)(ws + o_als0);
  float* pald0  = (float*)(ws + o_ald0);
  float* pals1  = (float*)(ws + o_als1);
  float* pald1  = (float*)(ws + o_ald1);
  int*   rowptr = (int*)(ws + o_rowptr);
  int*   cursor = (int*)(ws + o_cursor);
  int*   csrsrc = (int*)(ws + o_csrsrc);
  int*   csrdst = (int*)(ws + o_csrdst);
  __half* ale1h = (__half*)(ws + o_ale1);
  __half* p0h   = (__half*)(ws + o_p0);
  __half* p1h   = (__half*)(ws + o_p1);
  float* sarr   = (float*)(ws + o_sarr);
  ushort* Bhi   = (ushort*)(ws + o_Bhi);
  ushort* Blo   = (ushort*)(ws + o_Blo);
  int*   bsum   = (int*)(ws + o_bsum);
  int*   bpre   = (int*)(ws + o_bpre);
  int*   deg    = (int*)(ws + o_deg);
  float* sumea  = (float*)(ws + o_sumea);
  float* sumpool= (float*)(ws + o_sumpool);
  unsigned* maxkey = (unsigned*)(ws + o_maxkey);
  float* attpool= (float*)(ws + o_attpool);
  float* ssum   = (float*)(ws + o_ssum);
  float* small  = (float*)(ws + o_small);

  hipMemsetAsync(ws + zstart, 0, zend - zstart, stream);

  int eb = (int)((E_ + 255)/256);          // 3125
  int nb_wave = (int)((N_*64 + 255)/256);  // 12500 (one wave per node)
  int gb = (int)((N_ + 31)/32);            // 1563 gemm blocks
  int sb = (int)((N_ + 255)/256);          // 196 scan blocks

  k_pre    <<<eb, 256, 0, stream>>>(ei, deg, ea, sumea, W1, Bhi, Blo);
  k_scan1  <<<sb, 256, 0, stream>>>(deg, bsum);
  k_scan2  <<<1, 256, 0, stream>>>(bsum, bpre, sb, rowptr,
                                   We0, ae0, We1, ae1, sumea, small);
  k_scan3  <<<sb, 256, 0, stream>>>(deg, bpre, rowptr, cursor);
  k_h0     <<<nb_wave, 256, 0, stream>>>(x, W0, as0, ad0, bufH, pals0, pald0);
  k_scatter<<<eb, 256, 0, stream>>>(ei, ea, cursor, csrsrc, csrdst,
                                    ale1h, p0h, small, pals0, pald0);
  k_agg<float,true>  <<<nb_wave, 256, 0, stream>>>(bufH, pals0, pald0, rowptr, csrsrc,
                                         p0h, small, 32, b0, bufF);   // x1 fp32
  k_gemm   <<<gb, 256, 0, stream>>>(bufF, Bhi, Blo, bufH, as1, ad1, pals1, pald1);
  k_palpha1<<<eb, 256, 0, stream>>>(csrsrc, csrdst, ale1h, pals1, pald1, p1h);
  k_agg<__half,false><<<nb_wave, 256, 0, stream>>>(bufH, pals1, pald1, rowptr, csrsrc,
                                         p1h, small, 36, b1, h2h);    // h2 fp16
  k_pool1  <<<256, 256, 0, stream>>>(h2h, sumpool, maxkey);
  k_atts   <<<1024, 256, 0, stream>>>(h2h, sumpool, sarr, ssum);
  k_attp   <<<256, 256, 0, stream>>>(h2h, sarr, ssum, attpool);
  k_mlp    <<<1, 512, 0, stream>>>(sumpool, maxkey, attpool,
                                   Wm1, bm1, Wm2, bm2, Wm3, bm3, out);
}

// Round 6
// 533.594 us; speedup vs baseline: 1.0669x; 1.0669x over previous
//
#include <hip/hip_runtime.h>
#include <hip/hip_fp16.h>
#include <type_traits>

static const long long N_ = 50000;
static const long long E_ = 800000;
static const int NCOPY = 8;
#define LOG2E 1.44269504088896f

typedef __attribute__((ext_vector_type(8))) short bf16x8;
typedef __attribute__((ext_vector_type(4))) float f32x4;

__device__ __forceinline__ float lrelu(float x){ return x >= 0.f ? x : 0.2f*x; }
__device__ __forceinline__ unsigned fkey(float x){
  unsigned u = __float_as_uint(x);
  return (u & 0x80000000u) ? ~u : (u | 0x80000000u);
}
__device__ __forceinline__ float unfkey(unsigned k){
  return __uint_as_float((k & 0x80000000u) ? (k & 0x7fffffffu) : ~k);
}
__device__ __forceinline__ unsigned h2u(__half2 h){ return *(unsigned*)&h; }

// ---- fused prologue: replicated deg histogram (+rank) + ea col sums + W1 prep ----
__global__ void k_pre(const int* __restrict__ ei, int* __restrict__ deg8,
                      unsigned char* __restrict__ rank,
                      const float* __restrict__ ea, float* __restrict__ sum_ea,
                      const float* __restrict__ W1, ushort* __restrict__ Bhi,
                      ushort* __restrict__ Blo){
  int t = threadIdx.x;
  long long e = (long long)blockIdx.x*256 + t;
  if (e < E_){
    int d = ei[E_ + e];
    int copy = blockIdx.x & (NCOPY-1);
    int old = atomicAdd(&deg8[copy*(int)N_ + d], 1);
    rank[e] = (unsigned char)old;
  }
  if (blockIdx.x < 256){
    int k = blockIdx.x, n = t;
    float v = W1[k*256+n];
    unsigned u = __float_as_uint(v);
    ushort hi = (ushort)(u>>16);
    float rem = v - __uint_as_float(u & 0xffff0000u);
    unsigned ur = __float_as_uint(rem);
    ushort lo = (ushort)((ur + 0x7fff + ((ur>>16)&1)) >> 16);
    int tl = n>>4, kb = k>>5, q = (k>>3)&3, j = k&7;
    long long idx = ((((long long)tl*8+kb)*64 + q*16 + (n&15))<<3) + j;
    Bhi[idx] = hi; Blo[idx] = lo;
  }
  __shared__ float lds[256];
  float s = 0.f;
  for (long long i = (long long)blockIdx.x*256 + t; i < E_*4; i += (long long)gridDim.x*256)
    s += ea[i];
  lds[t] = s; __syncthreads();
  for (int st=128; st>=4; st>>=1){ if (t<st) lds[t] += lds[t+st]; __syncthreads(); }
  if (t<4) atomicAdd(&sum_ea[t], lds[t]);
}

// ---- scan phase 1: per-block sums of total deg ----
__global__ void k_scan1(const int* __restrict__ deg8, int* __restrict__ bsum){
  __shared__ int lds[256];
  int t = threadIdx.x;
  long long idx = (long long)blockIdx.x*256 + t;
  int v = 0;
  if (idx < N_){
    #pragma unroll
    for (int c=0;c<NCOPY;c++) v += deg8[c*(int)N_ + idx];
  }
  lds[t] = v;
  __syncthreads();
  for (int st=128; st>=1; st>>=1){ if (t<st) lds[t] += lds[t+st]; __syncthreads(); }
  if (t==0) bsum[blockIdx.x] = lds[0];
}

// ---- phase 2: scan block sums + fused "small" precompute (log2-scaled) ----
// small layout: [0..15]=Ae0*log2e, [16..31]=Ae1*log2e, [32..35]=loop0, [36..39]=loop1
__global__ void k_scan2(const int* __restrict__ bsum, int* __restrict__ bpre, int nb,
                        int* __restrict__ rowptr,
                        const float* __restrict__ We0, const float* __restrict__ ae0,
                        const float* __restrict__ We1, const float* __restrict__ ae1,
                        const float* __restrict__ sum_ea, float* __restrict__ small){
  __shared__ int lds[256];
  int t = threadIdx.x;
  int v = (t < nb) ? bsum[t] : 0;
  lds[t] = v; __syncthreads();
  for (int off=1; off<256; off<<=1){
    int add = (t>=off) ? lds[t-off] : 0;
    __syncthreads();
    lds[t] += add;
    __syncthreads();
  }
  if (t < nb) bpre[t] = lds[t] - v;     // exclusive
  if (t == 0) rowptr[N_] = (int)E_;
  if (t < 32){
    int l = t>>4, f = (t>>2)&3, h = t&3;
    const float* We = l ? We1 : We0;
    const float* ae = l ? ae1 : ae0;
    float s = 0.f;
    for (int cc=0; cc<64; cc++) s += We[f*256 + h*64 + cc]*ae[h*64+cc];
    small[l*16 + f*4 + h] = s * LOG2E;
  }
  __syncthreads();
  if (t < 8){
    int l = t>>2, h = t&3;
    const float* Ae = small + l*16;       // already scaled
    const float invE = 1.f/(float)E_;
    float s = 0.f;
    for (int f=0; f<4; f++) s += sum_ea[f]*invE*Ae[f*4+h];
    small[32 + l*4 + h] = s;
  }
}

// ---- phase 3: local scan + block offset -> rowptr + per-copy bases ----
__global__ void k_scan3(const int* __restrict__ deg8, const int* __restrict__ bpre,
                        int* __restrict__ rowptr, int* __restrict__ base){
  __shared__ int lds[256];
  int t = threadIdx.x;
  long long idx = (long long)blockIdx.x*256 + t;
  int dd[NCOPY]; int v = 0;
  if (idx < N_){
    #pragma unroll
    for (int c=0;c<NCOPY;c++){ dd[c] = deg8[c*(int)N_ + idx]; v += dd[c]; }
  }
  lds[t] = v; __syncthreads();
  for (int off=1; off<256; off<<=1){
    int add = (t>=off) ? lds[t-off] : 0;
    __syncthreads();
    lds[t] += add;
    __syncthreads();
  }
  if (idx < N_){
    int rp = bpre[blockIdx.x] + lds[t] - v;
    rowptr[idx] = rp;
    int cum = rp;
    #pragma unroll
    for (int c=0;c<NCOPY;c++){ base[c*(int)N_ + idx] = cum; cum += dd[c]; }
  }
}

// ---- h0 = x @ W0 (K=5), stored fp16; als0/ald0 (log2-scaled) ----
__global__ void k_h0(const float* __restrict__ x, const float* __restrict__ W0,
                     const float* __restrict__ as0, const float* __restrict__ ad0,
                     __half* __restrict__ h0, float* __restrict__ als, float* __restrict__ ald){
  int wid = (int)(((long long)blockIdx.x*blockDim.x + threadIdx.x) >> 6);
  int lane = threadIdx.x & 63;
  if (wid >= (int)N_) return;
  const float* xr = x + wid*5;
  float xv[5];
  #pragma unroll
  for (int f=0; f<5; f++) xv[f] = xr[f];
  int c = lane*4;
  float a0=0,a1=0,a2=0,a3=0;
  #pragma unroll
  for (int f=0; f<5; f++){
    const float* wr = W0 + f*256 + c;
    a0 += xv[f]*wr[0]; a1 += xv[f]*wr[1]; a2 += xv[f]*wr[2]; a3 += xv[f]*wr[3];
  }
  uint2 pk = make_uint2(h2u(__floats2half2_rn(a0,a1)), h2u(__floats2half2_rn(a2,a3)));
  *(uint2*)(h0 + wid*256 + c) = pk;
  const float* asp = as0 + c;
  const float* adp = ad0 + c;
  float ss = a0*asp[0]+a1*asp[1]+a2*asp[2]+a3*asp[3];
  float dd = a0*adp[0]+a1*adp[1]+a2*adp[2]+a3*adp[3];
  int head = lane>>4;
  #pragma unroll
  for (int m=1; m<16; m<<=1){ ss += __shfl_xor(ss, m); dd += __shfl_xor(dd, m); }
  if ((lane&15)==0){ als[wid*4+head]=ss*LOG2E; ald[wid*4+head]=dd*LOG2E; }
}

// ---- scatter (atomic-free): pos = base[copy][d] + rank[e]; fused p0 + ale1 ----
__global__ void k_scatter(const int* __restrict__ ei, const float* __restrict__ ea,
                          const int* __restrict__ base, const unsigned char* __restrict__ rank,
                          int2* __restrict__ csr2, uint4* __restrict__ pe,
                          const float* __restrict__ small,
                          const float* __restrict__ als0, const float* __restrict__ ald0){
  long long e = (long long)blockIdx.x*256 + threadIdx.x;
  if (e >= E_) return;
  int s = ei[e], d = ei[E_+e];
  int copy = blockIdx.x & (NCOPY-1);
  int pos = base[copy*(int)N_ + d] + (int)rank[e];
  csr2[pos] = make_int2(s, d);
  float4 v = *(const float4*)(ea + e*4);
  float4 As = *(const float4*)(als0 + s*4);
  float4 Ad = *(const float4*)(ald0 + d*4);
  float as_[4] = {As.x,As.y,As.z,As.w};
  float ad_[4] = {Ad.x,Ad.y,Ad.z,Ad.w};
  float p0[4], o1[4];
  #pragma unroll
  for (int h=0; h<4; h++){
    float a0 = v.x*small[0+h]  + v.y*small[4+h]  + v.z*small[8+h]  + v.w*small[12+h];
    p0[h] = exp2f(lrelu(as_[h] + ad_[h] + a0));
    o1[h] = v.x*small[16+h] + v.y*small[20+h] + v.z*small[24+h] + v.w*small[28+h];
  }
  uint4 pk = make_uint4(h2u(__floats2half2_rn(p0[0],p0[1])),
                        h2u(__floats2half2_rn(p0[2],p0[3])),
                        h2u(__floats2half2_rn(o1[0],o1[1])),
                        h2u(__floats2half2_rn(o1[2],o1[3])));
  pe[pos] = pk;
}

// ---- layer-1 p: edge-parallel exp2(lrelu(als1[s]+ald1[d]+ale1)) ----
__global__ void k_palpha1(const int2* __restrict__ csr2, const uint4* __restrict__ pe,
                          const float* __restrict__ als1, const float* __restrict__ ald1,
                          __half* __restrict__ p1h){
  long long i = (long long)blockIdx.x*256 + threadIdx.x;
  if (i >= E_) return;
  int2 sd = csr2[i];
  float4 As = *(const float4*)(als1 + sd.x*4);
  float4 Ad = *(const float4*)(ald1 + sd.y*4);
  uint4 pk = pe[i];
  float2 e01 = __half22float2(*(__half2*)&pk.z);
  float2 e23 = __half22float2(*(__half2*)&pk.w);
  float p0 = exp2f(lrelu(As.x+Ad.x+e01.x));
  float p1 = exp2f(lrelu(As.y+Ad.y+e01.y));
  float p2 = exp2f(lrelu(As.z+Ad.z+e23.x));
  float p3 = exp2f(lrelu(As.w+Ad.w+e23.y));
  uint2 o = make_uint2(h2u(__floats2half2_rn(p0,p1)), h2u(__floats2half2_rn(p2,p3)));
  *(uint2*)(p1h + i*4) = o;
}

// ---- GAT aggregation: one wave/node; 2 edges per wave (16B/lane), 4-pair unroll ----
template<typename OutT, bool RELU>
__global__ __launch_bounds__(256) void k_agg(const __half* __restrict__ hin,
    const float* __restrict__ als, const float* __restrict__ ald,
    const int* __restrict__ rowptr, const int2* __restrict__ csr2,
    const __half* __restrict__ ph, int pstride,
    const float* __restrict__ small, int loop_off,
    const float* __restrict__ bias, OutT* __restrict__ out){
  int wid = (int)(((long long)blockIdx.x*256 + threadIdx.x) >> 6);
  int lane = threadIdx.x & 63;
  if (wid >= (int)N_) return;
  int half_ = lane>>5, l5 = lane&31;
  int head = l5>>3, c8 = l5*8;
  const uint4* hp = (const uint4*)hin;
  float a[8]; float den;
  // self-loop (lower half only; upper half starts empty)
  {
    float pS = exp2f(lrelu(als[wid*4+head] + ald[wid*4+head] + small[loop_off+head]));
    float pp = (half_==0) ? pS : 0.f;
    uint4 r = hp[wid*32 + l5];
    float2 f0 = __half22float2(*(__half2*)&r.x);
    float2 f1 = __half22float2(*(__half2*)&r.y);
    float2 f2 = __half22float2(*(__half2*)&r.z);
    float2 f3 = __half22float2(*(__half2*)&r.w);
    den = pp;
    a[0]=pp*f0.x; a[1]=pp*f0.y; a[2]=pp*f1.x; a[3]=pp*f1.y;
    a[4]=pp*f2.x; a[5]=pp*f2.y; a[6]=pp*f3.x; a[7]=pp*f3.y;
  }
  int beg = rowptr[wid], end = rowptr[wid+1];
  int i = beg;
  for (; i+7 < end; i += 8){
    int   sv[4]; float pv[4]; uint4 rr[4];
    #pragma unroll
    for (int k=0;k<4;k++){
      int e = i + 2*k + half_;
      sv[k] = csr2[e].x;
      pv[k] = __half2float(ph[e*pstride + head]);
    }
    #pragma unroll
    for (int k=0;k<4;k++) rr[k] = hp[sv[k]*32 + l5];
    #pragma unroll
    for (int k=0;k<4;k++){
      float2 f0 = __half22float2(*(__half2*)&rr[k].x);
      float2 f1 = __half22float2(*(__half2*)&rr[k].y);
      float2 f2 = __half22float2(*(__half2*)&rr[k].z);
      float2 f3 = __half22float2(*(__half2*)&rr[k].w);
      float p = pv[k];
      den += p;
      a[0]+=p*f0.x; a[1]+=p*f0.y; a[2]+=p*f1.x; a[3]+=p*f1.y;
      a[4]+=p*f2.x; a[5]+=p*f2.y; a[6]+=p*f3.x; a[7]+=p*f3.y;
    }
  }
  for (; i < end; i += 2){
    int e = i + half_;
    bool act = (e < end);
    int ee = act ? e : (end-1);
    int s0 = csr2[ee].x;
    float p = act ? __half2float(ph[ee*pstride + head]) : 0.f;
    uint4 r = hp[s0*32 + l5];
    float2 f0 = __half22float2(*(__half2*)&r.x);
    float2 f1 = __half22float2(*(__half2*)&r.y);
    float2 f2 = __half22float2(*(__half2*)&r.z);
    float2 f3 = __half22float2(*(__half2*)&r.w);
    den += p;
    a[0]+=p*f0.x; a[1]+=p*f0.y; a[2]+=p*f1.x; a[3]+=p*f1.y;
    a[4]+=p*f2.x; a[5]+=p*f2.y; a[6]+=p*f3.x; a[7]+=p*f3.y;
  }
  // merge halves
  den += __shfl_xor(den, 32);
  #pragma unroll
  for (int j=0;j<8;j++) a[j] += __shfl_xor(a[j], 32);
  if (half_ == 0){
    float inv = 1.f/(den + 1e-16f);
    float4 b0 = *(const float4*)(bias + c8);
    float4 b1 = *(const float4*)(bias + c8 + 4);
    float o[8];
    o[0]=a[0]*inv+b0.x; o[1]=a[1]*inv+b0.y; o[2]=a[2]*inv+b0.z; o[3]=a[3]*inv+b0.w;
    o[4]=a[4]*inv+b1.x; o[5]=a[5]*inv+b1.y; o[6]=a[6]*inv+b1.z; o[7]=a[7]*inv+b1.w;
    if (RELU){
      #pragma unroll
      for (int j=0;j<8;j++) o[j] = fmaxf(o[j], 0.f);
    }
    if constexpr (std::is_same<OutT,__half>::value){
      uint4 qk = make_uint4(h2u(__floats2half2_rn(o[0],o[1])), h2u(__floats2half2_rn(o[2],o[3])),
                            h2u(__floats2half2_rn(o[4],o[5])), h2u(__floats2half2_rn(o[6],o[7])));
      *(uint4*)(out + wid*256 + c8) = qk;
    } else {
      *(float4*)(out + wid*256 + c8)     = make_float4(o[0],o[1],o[2],o[3]);
      *(float4*)(out + wid*256 + c8 + 4) = make_float4(o[4],o[5],o[6],o[7]);
    }
  }
}

// ---- h1 = x1 @ W1 via split-bf16 MFMA (3 products); fp16 out; fused als1/ald1 ----
__global__ __launch_bounds__(256) void k_gemm(const float* __restrict__ A,
    const ushort* __restrict__ Bhi, const ushort* __restrict__ Blo,
    __half* __restrict__ Ch, const float* __restrict__ as1, const float* __restrict__ ad1,
    float* __restrict__ als, float* __restrict__ ald){
  __shared__ ushort Ah[32*264];
  __shared__ ushort Al[32*264];
  int t = threadIdx.x;
  long long base = (long long)blockIdx.x*32;
  for (int i=t; i<2048; i+=256){
    int r = i>>6, q4 = i&63;
    float4 v = make_float4(0.f,0.f,0.f,0.f);
    if (base + r < N_) v = *(const float4*)(A + (base+r)*256 + q4*4);
    float vv[4] = {v.x,v.y,v.z,v.w};
    ushort hh[4], ll[4];
    #pragma unroll
    for (int e=0;e<4;e++){
      unsigned u = __float_as_uint(vv[e]);
      hh[e] = (ushort)(u>>16);
      float rem = vv[e] - __uint_as_float(u & 0xffff0000u);
      unsigned ur = __float_as_uint(rem);
      ll[e] = (ushort)((ur + 0x7fff + ((ur>>16)&1)) >> 16);
    }
    int off = r*264 + q4*4;
    *(ushort4*)(Ah+off) = make_ushort4(hh[0],hh[1],hh[2],hh[3]);
    *(ushort4*)(Al+off) = make_ushort4(ll[0],ll[1],ll[2],ll[3]);
  }
  __syncthreads();
  int w = t>>6, lane = t&63, m = lane&15, q = lane>>4;
  int rbase = (w>>1)*16;
  int nhalf = (w&1)*8;
  f32x4 acc[8];
  #pragma unroll
  for (int i=0;i<8;i++) acc[i] = (f32x4){0.f,0.f,0.f,0.f};
  for (int kb=0; kb<8; kb++){
    int aoff = (rbase+m)*264 + kb*32 + q*8;
    bf16x8 ah = *(const bf16x8*)(Ah + aoff);
    bf16x8 al = *(const bf16x8*)(Al + aoff);
    #pragma unroll
    for (int tt=0; tt<8; tt++){
      long long bidx = ((((long long)(nhalf+tt)*8+kb)*64 + lane)<<3);
      bf16x8 bh = *(const bf16x8*)(Bhi + bidx);
      bf16x8 bl = *(const bf16x8*)(Blo + bidx);
      acc[tt] = __builtin_amdgcn_mfma_f32_16x16x32_bf16(ah, bh, acc[tt], 0,0,0);
      acc[tt] = __builtin_amdgcn_mfma_f32_16x16x32_bf16(al, bh, acc[tt], 0,0,0);
      acc[tt] = __builtin_amdgcn_mfma_f32_16x16x32_bf16(ah, bl, acc[tt], 0,0,0);
    }
  }
  float ssv[4][2], ddv[4][2];
  #pragma unroll
  for (int r=0;r<4;r++){ ssv[r][0]=0.f; ssv[r][1]=0.f; ddv[r][0]=0.f; ddv[r][1]=0.f; }
  #pragma unroll
  for (int tt=0; tt<8; tt++){
    int col = (nhalf+tt)*16 + m;
    float as_ = as1[col], ad_ = ad1[col];
    int hh = tt>>2;
    #pragma unroll
    for (int r=0;r<4;r++){
      ssv[r][hh] += acc[tt][r]*as_;
      ddv[r][hh] += acc[tt][r]*ad_;
    }
  }
  #pragma unroll
  for (int r=0;r<4;r++){
    #pragma unroll
    for (int hh=0; hh<2; hh++){
      #pragma unroll
      for (int mm=1; mm<16; mm<<=1){
        ssv[r][hh] += __shfl_xor(ssv[r][hh], mm);
        ddv[r][hh] += __shfl_xor(ddv[r][hh], mm);
      }
    }
  }
  #pragma unroll
  for (int r=0;r<4;r++){
    long long grow = base + rbase + q*4 + r;
    if (grow < N_){
      #pragma unroll
      for (int tt=0; tt<8; tt++)
        Ch[grow*256 + (nhalf+tt)*16 + m] = __float2half(acc[tt][r]);
      if (m==0){
        int hb = (w&1)*2;
        als[grow*4 + hb+0] = ssv[r][0]*LOG2E;
        ald[grow*4 + hb+0] = ddv[r][0]*LOG2E;
        als[grow*4 + hb+1] = ssv[r][1]*LOG2E;
        ald[grow*4 + hb+1] = ddv[r][1]*LOG2E;
      }
    }
  }
}

// ---- column-wise sum & max over nodes (fp16 h2) ----
__global__ void k_pool1(const __half* __restrict__ h2, float* __restrict__ sum_pool,
                        unsigned* __restrict__ maxkey){
  int c = threadIdx.x; // 256
  float s = 0.f; float m = -3.4e38f;
  for (long long n = blockIdx.x; n < N_; n += gridDim.x){
    float v = __half2float(h2[n*256+c]); s += v; m = fmaxf(m, v);
  }
  atomicAdd(&sum_pool[c], s);
  atomicMax(&maxkey[c], fkey(m));
}

// ---- s[n] = dot(h2[n], mean_pool); accumulate sum(exp(s)) directly ----
__global__ void k_atts(const __half* __restrict__ h2, const float* __restrict__ sum_pool,
                       float* __restrict__ sarr, float* __restrict__ ssum){
  __shared__ float lsum[4];
  int t = threadIdx.x; int lane = t&63; int w = t>>6;
  const float invN = 1.f/(float)N_;
  int c = lane*4;
  float4 mp = *(const float4*)(sum_pool + c);
  float esum = 0.f;
  for (long long wid = (long long)blockIdx.x*4 + w; wid < N_; wid += (long long)gridDim.x*4){
    uint2 pk = *(const uint2*)(h2 + wid*256 + c);
    float2 a01 = __half22float2(*(__half2*)&pk.x);
    float2 a23 = __half22float2(*(__half2*)&pk.y);
    float s = (a01.x*mp.x + a01.y*mp.y + a23.x*mp.z + a23.y*mp.w)*invN;
    #pragma unroll
    for (int m=1; m<64; m<<=1) s += __shfl_xor(s, m);
    if (lane==0){ sarr[wid] = s; esum += __expf(s); }
  }
  if (lane==0) lsum[w] = esum;
  __syncthreads();
  if (t==0) atomicAdd(ssum, lsum[0]+lsum[1]+lsum[2]+lsum[3]);
}

// ---- att_pool[c] = sum_n h2[n][c]*exp(s[n])/ssum ----
__global__ void k_attp(const __half* __restrict__ h2, const float* __restrict__ sarr,
                       const float* __restrict__ ssum, float* __restrict__ att_pool){
  int c = threadIdx.x; // 256
  float inv = 1.f/(*ssum);
  float acc = 0.f;
  for (long long n = blockIdx.x; n < N_; n += gridDim.x){
    float w = __expf(sarr[n])*inv;
    acc += __half2float(h2[n*256+c])*w;
  }
  atomicAdd(&att_pool[c], acc);
}

// ---- final MLP: [768] -> 128 -> 64 -> 128, split-K across 512 threads ----
__global__ void k_mlp(const float* __restrict__ sum_pool, const unsigned* __restrict__ maxkey,
                      const float* __restrict__ att_pool,
                      const float* __restrict__ Wm1, const float* __restrict__ bm1,
                      const float* __restrict__ Wm2, const float* __restrict__ bm2,
                      const float* __restrict__ Wm3, const float* __restrict__ bm3,
                      float* __restrict__ out){
  __shared__ float comb[768];
  __shared__ float z1p[4][128]; __shared__ float z1[128];
  __shared__ float z2p[8][64];  __shared__ float z2[64];
  __shared__ float z3p[4][128];
  int t = threadIdx.x; // 512
  const float invN = 1.f/(float)N_;
  for (int i=t; i<768; i+=512){
    float v;
    if (i < 256)      v = sum_pool[i]*invN;
    else if (i < 512) v = unfkey(maxkey[i-256]);
    else              v = att_pool[i-512];
    comb[i] = v;
  }
  __syncthreads();
  { int n = t&127, part = t>>7;
    float a = 0.f;
    for (int f=part*192; f<part*192+192; f++) a += comb[f]*Wm1[f*128+n];
    z1p[part][n] = a;
  }
  __syncthreads();
  if (t < 128)
    z1[t] = fmaxf(bm1[t] + z1p[0][t]+z1p[1][t]+z1p[2][t]+z1p[3][t], 0.f);
  __syncthreads();
  { int n = t&63, part = t>>6;
    float a = 0.f;
    for (int f=part*16; f<part*16+16; f++) a += z1[f]*Wm2[f*64+n];
    z2p[part][n] = a;
  }
  __syncthreads();
  if (t < 64){
    float a = bm2[t];
    #pragma unroll
    for (int p=0;p<8;p++) a += z2p[p][t];
    z2[t] = fmaxf(a, 0.f);
  }
  __syncthreads();
  { int n = t&127, part = t>>7;
    float a = 0.f;
    for (int f=part*16; f<part*16+16; f++) a += z2[f]*Wm3[f*128+n];
    z3p[part][n] = a;
  }
  __syncthreads();
  if (t < 128)
    out[t] = bm3[t] + z3p[0][t]+z3p[1][t]+z3p[2][t]+z3p[3][t];
}

extern "C" void kernel_launch(void* const* d_in, const int* in_sizes, int n_in,
                              void* d_out, int out_size, void* d_ws, size_t ws_size,
                              hipStream_t stream){
  (void)in_sizes; (void)n_in; (void)out_size; (void)ws_size;
  const float* x   = (const float*)d_in[0];
  const int*   ei  = (const int*)d_in[1];
  const float* ea  = (const float*)d_in[2];
  const float* W0  = (const float*)d_in[3];
  const float* as0 = (const float*)d_in[4];
  const float* ad0 = (const float*)d_in[5];
  const float* We0 = (const float*)d_in[6];
  const float* ae0 = (const float*)d_in[7];
  const float* b0  = (const float*)d_in[8];
  const float* W1  = (const float*)d_in[9];
  const float* as1 = (const float*)d_in[10];
  const float* ad1 = (const float*)d_in[11];
  const float* We1 = (const float*)d_in[12];
  const float* ae1 = (const float*)d_in[13];
  const float* b1  = (const float*)d_in[14];
  const float* Wm1 = (const float*)d_in[15];
  const float* bm1 = (const float*)d_in[16];
  const float* Wm2 = (const float*)d_in[17];
  const float* bm2 = (const float*)d_in[18];
  const float* Wm3 = (const float*)d_in[19];
  const float* bm3 = (const float*)d_in[20];
  float* out = (float*)d_out;

  char* ws = (char*)d_ws;
  size_t o = 0;
  auto alloc = [&](size_t bytes)->size_t{
    size_t r = o; o = (o + bytes + 255) & ~(size_t)255; return r;
  };
  size_t o_bufF   = alloc((size_t)N_*256*4);   // x1 (fp32), then h2 (fp16)
  size_t o_bufH   = alloc((size_t)N_*256*2);   // h0, then h1 (fp16)
  size_t o_als0   = alloc((size_t)N_*4*4);
  size_t o_ald0   = alloc((size_t)N_*4*4);
  size_t o_als1   = alloc((size_t)N_*4*4);
  size_t o_ald1   = alloc((size_t)N_*4*4);
  size_t o_rowptr = alloc((size_t)(N_+1)*4);
  size_t o_csr2   = alloc((size_t)E_*8);       // int2 (src,dst)
  size_t o_pe     = alloc((size_t)E_*16);      // uint4: p0 x4 fp16 | ale1 x4 fp16
  size_t o_p1     = alloc((size_t)E_*4*2);     // fp16 x4 per edge (layer-1 p)
  size_t o_rank   = alloc((size_t)E_);         // uchar rank within (copy,dst)
  size_t o_base   = alloc((size_t)NCOPY*N_*4); // per-copy CSR bases
  size_t o_sarr   = alloc((size_t)N_*4);
  size_t o_Bhi    = alloc((size_t)256*256*2);
  size_t o_Blo    = alloc((size_t)256*256*2);
  size_t o_bsum   = alloc(256*4);
  size_t o_bpre   = alloc(256*4);
  // --- zero block ---
  size_t zstart   = o;
  size_t o_deg8   = alloc((size_t)NCOPY*N_*4);
  size_t o_sumea  = alloc(16);
  size_t o_sumpool= alloc(256*4);
  size_t o_maxkey = alloc(256*4);
  size_t o_attpool= alloc(256*4);
  size_t o_ssum   = alloc(4);
  size_t zend     = o;
  size_t o_small  = alloc(40*4);

  float*  bufF   = (float*)(ws + o_bufF);
  __half* bufH   = (__half*)(ws + o_bufH);
  __half* h2h    = (__half*)(ws + o_bufF);     // reuse bufF region for fp16 h2
  float* pals0  = (float*)(ws + o_als0);
  float* pald0  = (float*)(ws + o_ald0);
  float* pals1  = (float*)(ws + o_als1);
  float* pald1  = (float*)(ws + o_ald1);
  int*   rowptr = (int*)(ws + o_rowptr);
  int2*  csr2   = (int2*)(ws + o_csr2);
  uint4* pe     = (uint4*)(ws + o_pe);
  __half* p1h   = (__half*)(ws + o_p1);
  unsigned char* rank = (unsigned char*)(ws + o_rank);
  int*   base   = (int*)(ws + o_base);
  float* sarr   = (float*)(ws + o_sarr);
  ushort* Bhi   = (ushort*)(ws + o_Bhi);
  ushort* Blo   = (ushort*)(ws + o_Blo);
  int*   bsum   = (int*)(ws + o_bsum);
  int*   bpre   = (int*)(ws + o_bpre);
  int*   deg8   = (int*)(ws + o_deg8);
  float* sumea  = (float*)(ws + o_sumea);
  float* sumpool= (float*)(ws + o_sumpool);
  unsigned* maxkey = (unsigned*)(ws + o_maxkey);
  float* attpool= (float*)(ws + o_attpool);
  float* ssum   = (float*)(ws + o_ssum);
  float* small  = (float*)(ws + o_small);

  hipMemsetAsync(ws + zstart, 0, zend - zstart, stream);

  int eb = (int)((E_ + 255)/256);          // 3125
  int nb_wave = (int)((N_*64 + 255)/256);  // 12500 (one wave per node)
  int gb = (int)((N_ + 31)/32);            // 1563 gemm blocks
  int sb = (int)((N_ + 255)/256);          // 196 scan blocks

  k_pre    <<<eb, 256, 0, stream>>>(ei, deg8, rank, ea, sumea, W1, Bhi, Blo);
  k_scan1  <<<sb, 256, 0, stream>>>(deg8, bsum);
  k_scan2  <<<1, 256, 0, stream>>>(bsum, bpre, sb, rowptr,
                                   We0, ae0, We1, ae1, sumea, small);
  k_scan3  <<<sb, 256, 0, stream>>>(deg8, bpre, rowptr, base);
  k_h0     <<<nb_wave, 256, 0, stream>>>(x, W0, as0, ad0, bufH, pals0, pald0);
  k_scatter<<<eb, 256, 0, stream>>>(ei, ea, base, rank, csr2, pe,
                                    small, pals0, pald0);
  k_agg<float,true>  <<<nb_wave, 256, 0, stream>>>(bufH, pals0, pald0, rowptr, csr2,
                                         (const __half*)pe, 8, small, 32, b0, bufF);
  k_gemm   <<<gb, 256, 0, stream>>>(bufF, Bhi, Blo, bufH, as1, ad1, pals1, pald1);
  k_palpha1<<<eb, 256, 0, stream>>>(csr2, pe, pals1, pald1, p1h);
  k_agg<__half,false><<<nb_wave, 256, 0, stream>>>(bufH, pals1, pald1, rowptr, csr2,
                                         p1h, 4, small, 36, b1, h2h);
  k_pool1  <<<256, 256, 0, stream>>>(h2h, sumpool, maxkey);
  k_atts   <<<1024, 256, 0, stream>>>(h2h, sumpool, sarr, ssum);
  k_attp   <<<256, 256, 0, stream>>>(h2h, sarr, ssum, attpool);
  k_mlp    <<<1, 512, 0, stream>>>(sumpool, maxkey, attpool,
                                   Wm1, bm1, Wm2, bm2, Wm3, bm3, out);
}

// Round 7
// 494.880 us; speedup vs baseline: 1.1503x; 1.0782x over previous
//
#include <hip/hip_runtime.h>
#include <hip/hip_fp16.h>
#include <type_traits>

static const long long N_ = 50000;
static const long long E_ = 800000;
static const int NCOPY = 8;
#define LOG2E 1.44269504088896f

typedef __attribute__((ext_vector_type(8))) short bf16x8;
typedef __attribute__((ext_vector_type(4))) float f32x4;

__device__ __forceinline__ float lrelu(float x){ return x >= 0.f ? x : 0.2f*x; }
__device__ __forceinline__ unsigned fkey(float x){
  unsigned u = __float_as_uint(x);
  return (u & 0x80000000u) ? ~u : (u | 0x80000000u);
}
__device__ __forceinline__ float unfkey(unsigned k){
  return __uint_as_float((k & 0x80000000u) ? (k & 0x7fffffffu) : ~k);
}
__device__ __forceinline__ unsigned h2u(__half2 h){ return *(unsigned*)&h; }

// ---- prologue: replicated deg histogram (+rank) + W1 bf16-split prep ----
// (ea column sums moved to k_scan1: the 4-wide same-line atomicAdd from 3125
//  blocks serialized device-wide and dominated this kernel)
__global__ void k_pre(const int* __restrict__ ei, int* __restrict__ deg8,
                      unsigned char* __restrict__ rank,
                      const float* __restrict__ W1, ushort* __restrict__ Bhi,
                      ushort* __restrict__ Blo){
  int t = threadIdx.x;
  long long e = (long long)blockIdx.x*256 + t;
  if (e < E_){
    int d = ei[E_ + e];
    int copy = blockIdx.x & (NCOPY-1);
    int old = atomicAdd(&deg8[copy*(int)N_ + d], 1);
    rank[e] = (unsigned char)old;
  }
  if (blockIdx.x < 256){
    int k = blockIdx.x, n = t;
    float v = W1[k*256+n];
    unsigned u = __float_as_uint(v);
    ushort hi = (ushort)(u>>16);
    float rem = v - __uint_as_float(u & 0xffff0000u);
    unsigned ur = __float_as_uint(rem);
    ushort lo = (ushort)((ur + 0x7fff + ((ur>>16)&1)) >> 16);
    int tl = n>>4, kb = k>>5, q = (k>>3)&3, j = k&7;
    long long idx = ((((long long)tl*8+kb)*64 + q*16 + (n&15))<<3) + j;
    Bhi[idx] = hi; Blo[idx] = lo;
  }
}

// ---- scan phase 1: per-block sums of total deg + ea column partial sums ----
__global__ void k_scan1(const int* __restrict__ deg8, int* __restrict__ bsum,
                        const float* __restrict__ ea, float* __restrict__ eapart){
  __shared__ int lds[256];
  __shared__ float fl[256];
  int t = threadIdx.x;
  long long idx = (long long)blockIdx.x*256 + t;
  int v = 0;
  if (idx < N_){
    #pragma unroll
    for (int c=0;c<NCOPY;c++) v += deg8[c*(int)N_ + idx];
  }
  lds[t] = v;
  // ea partials: stride keeps col = i&3 == t&3
  float s = 0.f;
  for (long long i = (long long)blockIdx.x*256 + t; i < E_*4; i += (long long)gridDim.x*256)
    s += ea[i];
  fl[t] = s;
  __syncthreads();
  for (int st=128; st>=1; st>>=1){
    if (t<st) lds[t] += lds[t+st];
    if (t<st && st>=4) fl[t] += fl[t+st];
    __syncthreads();
  }
  if (t==0) bsum[blockIdx.x] = lds[0];
  if (t<4) eapart[blockIdx.x*4 + t] = fl[t];
}

// ---- phase 2: scan block sums + fused "small" precompute (log2-scaled) ----
// small layout: [0..15]=Ae0*log2e, [16..31]=Ae1*log2e, [32..35]=loop0, [36..39]=loop1
__global__ void k_scan2(const int* __restrict__ bsum, int* __restrict__ bpre, int nb,
                        int* __restrict__ rowptr,
                        const float* __restrict__ We0, const float* __restrict__ ae0,
                        const float* __restrict__ We1, const float* __restrict__ ae1,
                        const float* __restrict__ eapart, float* __restrict__ small){
  __shared__ int lds[256];
  __shared__ float sea[4];
  int t = threadIdx.x;
  int v = (t < nb) ? bsum[t] : 0;
  lds[t] = v; __syncthreads();
  for (int off=1; off<256; off<<=1){
    int add = (t>=off) ? lds[t-off] : 0;
    __syncthreads();
    lds[t] += add;
    __syncthreads();
  }
  if (t < nb) bpre[t] = lds[t] - v;     // exclusive
  if (t == 0) rowptr[N_] = (int)E_;
  if (t < 4){
    float s = 0.f;
    for (int b=0;b<nb;b++) s += eapart[b*4+t];
    sea[t] = s;
  }
  if (t < 32){
    int l = t>>4, f = (t>>2)&3, h = t&3;
    const float* We = l ? We1 : We0;
    const float* ae = l ? ae1 : ae0;
    float s = 0.f;
    for (int cc=0; cc<64; cc++) s += We[f*256 + h*64 + cc]*ae[h*64+cc];
    small[l*16 + f*4 + h] = s * LOG2E;
  }
  __syncthreads();
  if (t < 8){
    int l = t>>2, h = t&3;
    const float* Ae = small + l*16;       // already scaled
    const float invE = 1.f/(float)E_;
    float s = 0.f;
    for (int f=0; f<4; f++) s += sea[f]*invE*Ae[f*4+h];
    small[32 + l*4 + h] = s;
  }
}

// ---- phase 3: local scan + block offset -> rowptr + per-copy bases ----
__global__ void k_scan3(const int* __restrict__ deg8, const int* __restrict__ bpre,
                        int* __restrict__ rowptr, int* __restrict__ base){
  __shared__ int lds[256];
  int t = threadIdx.x;
  long long idx = (long long)blockIdx.x*256 + t;
  int dd[NCOPY]; int v = 0;
  if (idx < N_){
    #pragma unroll
    for (int c=0;c<NCOPY;c++){ dd[c] = deg8[c*(int)N_ + idx]; v += dd[c]; }
  }
  lds[t] = v; __syncthreads();
  for (int off=1; off<256; off<<=1){
    int add = (t>=off) ? lds[t-off] : 0;
    __syncthreads();
    lds[t] += add;
    __syncthreads();
  }
  if (idx < N_){
    int rp = bpre[blockIdx.x] + lds[t] - v;
    rowptr[idx] = rp;
    int cum = rp;
    #pragma unroll
    for (int c=0;c<NCOPY;c++){ base[c*(int)N_ + idx] = cum; cum += dd[c]; }
  }
}

// ---- h0 = x @ W0 (K=5), stored fp16; als0/ald0 (log2-scaled) ----
__global__ void k_h0(const float* __restrict__ x, const float* __restrict__ W0,
                     const float* __restrict__ as0, const float* __restrict__ ad0,
                     __half* __restrict__ h0, float* __restrict__ als, float* __restrict__ ald){
  int wid = (int)(((long long)blockIdx.x*blockDim.x + threadIdx.x) >> 6);
  int lane = threadIdx.x & 63;
  if (wid >= (int)N_) return;
  const float* xr = x + wid*5;
  float xv[5];
  #pragma unroll
  for (int f=0; f<5; f++) xv[f] = xr[f];
  int c = lane*4;
  float a0=0,a1=0,a2=0,a3=0;
  #pragma unroll
  for (int f=0; f<5; f++){
    const float* wr = W0 + f*256 + c;
    a0 += xv[f]*wr[0]; a1 += xv[f]*wr[1]; a2 += xv[f]*wr[2]; a3 += xv[f]*wr[3];
  }
  uint2 pk = make_uint2(h2u(__floats2half2_rn(a0,a1)), h2u(__floats2half2_rn(a2,a3)));
  *(uint2*)(h0 + wid*256 + c) = pk;
  const float* asp = as0 + c;
  const float* adp = ad0 + c;
  float ss = a0*asp[0]+a1*asp[1]+a2*asp[2]+a3*asp[3];
  float dd = a0*adp[0]+a1*adp[1]+a2*adp[2]+a3*adp[3];
  int head = lane>>4;
  #pragma unroll
  for (int m=1; m<16; m<<=1){ ss += __shfl_xor(ss, m); dd += __shfl_xor(dd, m); }
  if ((lane&15)==0){ als[wid*4+head]=ss*LOG2E; ald[wid*4+head]=dd*LOG2E; }
}

// ---- scatter (atomic-free): pos = base[copy][d] + rank[e]; fused p0 + ale1 ----
__global__ void k_scatter(const int* __restrict__ ei, const float* __restrict__ ea,
                          const int* __restrict__ base, const unsigned char* __restrict__ rank,
                          int2* __restrict__ csr2, uint4* __restrict__ pe,
                          const float* __restrict__ small,
                          const float* __restrict__ als0, const float* __restrict__ ald0){
  long long e = (long long)blockIdx.x*256 + threadIdx.x;
  if (e >= E_) return;
  int s = ei[e], d = ei[E_+e];
  int copy = blockIdx.x & (NCOPY-1);
  int pos = base[copy*(int)N_ + d] + (int)rank[e];
  csr2[pos] = make_int2(s, d);
  float4 v = *(const float4*)(ea + e*4);
  float4 As = *(const float4*)(als0 + s*4);
  float4 Ad = *(const float4*)(ald0 + d*4);
  float as_[4] = {As.x,As.y,As.z,As.w};
  float ad_[4] = {Ad.x,Ad.y,Ad.z,Ad.w};
  float p0[4], o1[4];
  #pragma unroll
  for (int h=0; h<4; h++){
    float a0 = v.x*small[0+h]  + v.y*small[4+h]  + v.z*small[8+h]  + v.w*small[12+h];
    p0[h] = exp2f(lrelu(as_[h] + ad_[h] + a0));
    o1[h] = v.x*small[16+h] + v.y*small[20+h] + v.z*small[24+h] + v.w*small[28+h];
  }
  uint4 pk = make_uint4(h2u(__floats2half2_rn(p0[0],p0[1])),
                        h2u(__floats2half2_rn(p0[2],p0[3])),
                        h2u(__floats2half2_rn(o1[0],o1[1])),
                        h2u(__floats2half2_rn(o1[2],o1[3])));
  pe[pos] = pk;
}

// ---- layer-1 p: edge-parallel exp2(lrelu(als1[s]+ald1[d]+ale1)) ----
__global__ void k_palpha1(const int2* __restrict__ csr2, const uint4* __restrict__ pe,
                          const float* __restrict__ als1, const float* __restrict__ ald1,
                          __half* __restrict__ p1h){
  long long i = (long long)blockIdx.x*256 + threadIdx.x;
  if (i >= E_) return;
  int2 sd = csr2[i];
  float4 As = *(const float4*)(als1 + sd.x*4);
  float4 Ad = *(const float4*)(ald1 + sd.y*4);
  uint4 pk = pe[i];
  float2 e01 = __half22float2(*(__half2*)&pk.z);
  float2 e23 = __half22float2(*(__half2*)&pk.w);
  float p0 = exp2f(lrelu(As.x+Ad.x+e01.x));
  float p1 = exp2f(lrelu(As.y+Ad.y+e01.y));
  float p2 = exp2f(lrelu(As.z+Ad.z+e23.x));
  float p3 = exp2f(lrelu(As.w+Ad.w+e23.y));
  uint2 o = make_uint2(h2u(__floats2half2_rn(p0,p1)), h2u(__floats2half2_rn(p2,p3)));
  *(uint2*)(p1h + i*4) = o;
}

// ---- GAT aggregation: one wave/node; 2 edges per wave (16B/lane), 4-pair unroll ----
template<typename OutT, bool RELU>
__global__ __launch_bounds__(256) void k_agg(const __half* __restrict__ hin,
    const float* __restrict__ als, const float* __restrict__ ald,
    const int* __restrict__ rowptr, const int2* __restrict__ csr2,
    const __half* __restrict__ ph, int pstride,
    const float* __restrict__ small, int loop_off,
    const float* __restrict__ bias, OutT* __restrict__ out){
  int wid = (int)(((long long)blockIdx.x*256 + threadIdx.x) >> 6);
  int lane = threadIdx.x & 63;
  if (wid >= (int)N_) return;
  int half_ = lane>>5, l5 = lane&31;
  int head = l5>>3, c8 = l5*8;
  const uint4* hp = (const uint4*)hin;
  float a[8]; float den;
  // self-loop (lower half only; upper half starts empty)
  {
    float pS = exp2f(lrelu(als[wid*4+head] + ald[wid*4+head] + small[loop_off+head]));
    float pp = (half_==0) ? pS : 0.f;
    uint4 r = hp[wid*32 + l5];
    float2 f0 = __half22float2(*(__half2*)&r.x);
    float2 f1 = __half22float2(*(__half2*)&r.y);
    float2 f2 = __half22float2(*(__half2*)&r.z);
    float2 f3 = __half22float2(*(__half2*)&r.w);
    den = pp;
    a[0]=pp*f0.x; a[1]=pp*f0.y; a[2]=pp*f1.x; a[3]=pp*f1.y;
    a[4]=pp*f2.x; a[5]=pp*f2.y; a[6]=pp*f3.x; a[7]=pp*f3.y;
  }
  int beg = rowptr[wid], end = rowptr[wid+1];
  int i = beg;
  for (; i+7 < end; i += 8){
    int   sv[4]; float pv[4]; uint4 rr[4];
    #pragma unroll
    for (int k=0;k<4;k++){
      int e = i + 2*k + half_;
      sv[k] = csr2[e].x;
      pv[k] = __half2float(ph[e*pstride + head]);
    }
    #pragma unroll
    for (int k=0;k<4;k++) rr[k] = hp[sv[k]*32 + l5];
    #pragma unroll
    for (int k=0;k<4;k++){
      float2 f0 = __half22float2(*(__half2*)&rr[k].x);
      float2 f1 = __half22float2(*(__half2*)&rr[k].y);
      float2 f2 = __half22float2(*(__half2*)&rr[k].z);
      float2 f3 = __half22float2(*(__half2*)&rr[k].w);
      float p = pv[k];
      den += p;
      a[0]+=p*f0.x; a[1]+=p*f0.y; a[2]+=p*f1.x; a[3]+=p*f1.y;
      a[4]+=p*f2.x; a[5]+=p*f2.y; a[6]+=p*f3.x; a[7]+=p*f3.y;
    }
  }
  for (; i < end; i += 2){
    int e = i + half_;
    bool act = (e < end);
    int ee = act ? e : (end-1);
    int s0 = csr2[ee].x;
    float p = act ? __half2float(ph[ee*pstride + head]) : 0.f;
    uint4 r = hp[s0*32 + l5];
    float2 f0 = __half22float2(*(__half2*)&r.x);
    float2 f1 = __half22float2(*(__half2*)&r.y);
    float2 f2 = __half22float2(*(__half2*)&r.z);
    float2 f3 = __half22float2(*(__half2*)&r.w);
    den += p;
    a[0]+=p*f0.x; a[1]+=p*f0.y; a[2]+=p*f1.x; a[3]+=p*f1.y;
    a[4]+=p*f2.x; a[5]+=p*f2.y; a[6]+=p*f3.x; a[7]+=p*f3.y;
  }
  // merge halves
  den += __shfl_xor(den, 32);
  #pragma unroll
  for (int j=0;j<8;j++) a[j] += __shfl_xor(a[j], 32);
  if (half_ == 0){
    float inv = 1.f/(den + 1e-16f);
    float4 b0 = *(const float4*)(bias + c8);
    float4 b1 = *(const float4*)(bias + c8 + 4);
    float o[8];
    o[0]=a[0]*inv+b0.x; o[1]=a[1]*inv+b0.y; o[2]=a[2]*inv+b0.z; o[3]=a[3]*inv+b0.w;
    o[4]=a[4]*inv+b1.x; o[5]=a[5]*inv+b1.y; o[6]=a[6]*inv+b1.z; o[7]=a[7]*inv+b1.w;
    if (RELU){
      #pragma unroll
      for (int j=0;j<8;j++) o[j] = fmaxf(o[j], 0.f);
    }
    if constexpr (std::is_same<OutT,__half>::value){
      uint4 qk = make_uint4(h2u(__floats2half2_rn(o[0],o[1])), h2u(__floats2half2_rn(o[2],o[3])),
                            h2u(__floats2half2_rn(o[4],o[5])), h2u(__floats2half2_rn(o[6],o[7])));
      *(uint4*)(out + wid*256 + c8) = qk;
    } else {
      *(float4*)(out + wid*256 + c8)     = make_float4(o[0],o[1],o[2],o[3]);
      *(float4*)(out + wid*256 + c8 + 4) = make_float4(o[4],o[5],o[6],o[7]);
    }
  }
}

// ---- h1 = x1 @ W1 via split-bf16 MFMA (3 products); fp16 out; fused als1/ald1 ----
__global__ __launch_bounds__(256) void k_gemm(const float* __restrict__ A,
    const ushort* __restrict__ Bhi, const ushort* __restrict__ Blo,
    __half* __restrict__ Ch, const float* __restrict__ as1, const float* __restrict__ ad1,
    float* __restrict__ als, float* __restrict__ ald){
  __shared__ ushort Ah[32*264];
  __shared__ ushort Al[32*264];
  int t = threadIdx.x;
  long long base = (long long)blockIdx.x*32;
  for (int i=t; i<2048; i+=256){
    int r = i>>6, q4 = i&63;
    float4 v = make_float4(0.f,0.f,0.f,0.f);
    if (base + r < N_) v = *(const float4*)(A + (base+r)*256 + q4*4);
    float vv[4] = {v.x,v.y,v.z,v.w};
    ushort hh[4], ll[4];
    #pragma unroll
    for (int e=0;e<4;e++){
      unsigned u = __float_as_uint(vv[e]);
      hh[e] = (ushort)(u>>16);
      float rem = vv[e] - __uint_as_float(u & 0xffff0000u);
      unsigned ur = __float_as_uint(rem);
      ll[e] = (ushort)((ur + 0x7fff + ((ur>>16)&1)) >> 16);
    }
    int off = r*264 + q4*4;
    *(ushort4*)(Ah+off) = make_ushort4(hh[0],hh[1],hh[2],hh[3]);
    *(ushort4*)(Al+off) = make_ushort4(ll[0],ll[1],ll[2],ll[3]);
  }
  __syncthreads();
  int w = t>>6, lane = t&63, m = lane&15, q = lane>>4;
  int rbase = (w>>1)*16;
  int nhalf = (w&1)*8;
  f32x4 acc[8];
  #pragma unroll
  for (int i=0;i<8;i++) acc[i] = (f32x4){0.f,0.f,0.f,0.f};
  for (int kb=0; kb<8; kb++){
    int aoff = (rbase+m)*264 + kb*32 + q*8;
    bf16x8 ah = *(const bf16x8*)(Ah + aoff);
    bf16x8 al = *(const bf16x8*)(Al + aoff);
    #pragma unroll
    for (int tt=0; tt<8; tt++){
      long long bidx = ((((long long)(nhalf+tt)*8+kb)*64 + lane)<<3);
      bf16x8 bh = *(const bf16x8*)(Bhi + bidx);
      bf16x8 bl = *(const bf16x8*)(Blo + bidx);
      acc[tt] = __builtin_amdgcn_mfma_f32_16x16x32_bf16(ah, bh, acc[tt], 0,0,0);
      acc[tt] = __builtin_amdgcn_mfma_f32_16x16x32_bf16(al, bh, acc[tt], 0,0,0);
      acc[tt] = __builtin_amdgcn_mfma_f32_16x16x32_bf16(ah, bl, acc[tt], 0,0,0);
    }
  }
  float ssv[4][2], ddv[4][2];
  #pragma unroll
  for (int r=0;r<4;r++){ ssv[r][0]=0.f; ssv[r][1]=0.f; ddv[r][0]=0.f; ddv[r][1]=0.f; }
  #pragma unroll
  for (int tt=0; tt<8; tt++){
    int col = (nhalf+tt)*16 + m;
    float as_ = as1[col], ad_ = ad1[col];
    int hh = tt>>2;
    #pragma unroll
    for (int r=0;r<4;r++){
      ssv[r][hh] += acc[tt][r]*as_;
      ddv[r][hh] += acc[tt][r]*ad_;
    }
  }
  #pragma unroll
  for (int r=0;r<4;r++){
    #pragma unroll
    for (int hh=0; hh<2; hh++){
      #pragma unroll
      for (int mm=1; mm<16; mm<<=1){
        ssv[r][hh] += __shfl_xor(ssv[r][hh], mm);
        ddv[r][hh] += __shfl_xor(ddv[r][hh], mm);
      }
    }
  }
  #pragma unroll
  for (int r=0;r<4;r++){
    long long grow = base + rbase + q*4 + r;
    if (grow < N_){
      #pragma unroll
      for (int tt=0; tt<8; tt++)
        Ch[grow*256 + (nhalf+tt)*16 + m] = __float2half(acc[tt][r]);
      if (m==0){
        int hb = (w&1)*2;
        als[grow*4 + hb+0] = ssv[r][0]*LOG2E;
        ald[grow*4 + hb+0] = ddv[r][0]*LOG2E;
        als[grow*4 + hb+1] = ssv[r][1]*LOG2E;
        ald[grow*4 + hb+1] = ddv[r][1]*LOG2E;
      }
    }
  }
}

// ---- column-wise sum & max over nodes (fp16 h2) ----
__global__ void k_pool1(const __half* __restrict__ h2, float* __restrict__ sum_pool,
                        unsigned* __restrict__ maxkey){
  int c = threadIdx.x; // 256
  float s = 0.f; float m = -3.4e38f;
  for (long long n = blockIdx.x; n < N_; n += gridDim.x){
    float v = __half2float(h2[n*256+c]); s += v; m = fmaxf(m, v);
  }
  atomicAdd(&sum_pool[c], s);
  atomicMax(&maxkey[c], fkey(m));
}

// ---- fused attention pool: s[n]=dot(h2[n],mp); accumulate ssum & att_raw ----
__global__ void k_atts(const __half* __restrict__ h2, const float* __restrict__ sum_pool,
                       float* __restrict__ ssum, float* __restrict__ att_raw){
  __shared__ float part[4][256];
  __shared__ float es[4];
  int t = threadIdx.x; int lane = t&63; int w = t>>6;
  const float invN = 1.f/(float)N_;
  int c = lane*4;
  float4 mp = *(const float4*)(sum_pool + c);
  float esum = 0.f;
  float acc0=0.f, acc1=0.f, acc2=0.f, acc3=0.f;
  for (long long wid = (long long)blockIdx.x*4 + w; wid < N_; wid += (long long)gridDim.x*4){
    uint2 pk = *(const uint2*)(h2 + wid*256 + c);
    float2 a01 = __half22float2(*(__half2*)&pk.x);
    float2 a23 = __half22float2(*(__half2*)&pk.y);
    float s = (a01.x*mp.x + a01.y*mp.y + a23.x*mp.z + a23.y*mp.w)*invN;
    #pragma unroll
    for (int m=1; m<64; m<<=1) s += __shfl_xor(s, m);
    float e = __expf(s);
    if (lane==0) esum += e;
    acc0 += e*a01.x; acc1 += e*a01.y; acc2 += e*a23.x; acc3 += e*a23.y;
  }
  part[w][c+0]=acc0; part[w][c+1]=acc1; part[w][c+2]=acc2; part[w][c+3]=acc3;
  if (lane==0) es[w] = esum;
  __syncthreads();
  if (t < 256){
    float v = part[0][t]+part[1][t]+part[2][t]+part[3][t];
    atomicAdd(&att_raw[t], v);
  }
  if (t==0) atomicAdd(ssum, es[0]+es[1]+es[2]+es[3]);
}

// ---- final MLP: [768] -> 128 -> 64 -> 128, split-K across 512 threads ----
__global__ void k_mlp(const float* __restrict__ sum_pool, const unsigned* __restrict__ maxkey,
                      const float* __restrict__ att_raw, const float* __restrict__ ssum,
                      const float* __restrict__ Wm1, const float* __restrict__ bm1,
                      const float* __restrict__ Wm2, const float* __restrict__ bm2,
                      const float* __restrict__ Wm3, const float* __restrict__ bm3,
                      float* __restrict__ out){
  __shared__ float comb[768];
  __shared__ float z1p[4][128]; __shared__ float z1[128];
  __shared__ float z2p[8][64];  __shared__ float z2[64];
  __shared__ float z3p[4][128];
  int t = threadIdx.x; // 512
  const float invN = 1.f/(float)N_;
  float invS = 1.f/(*ssum);
  for (int i=t; i<768; i+=512){
    float v;
    if (i < 256)      v = sum_pool[i]*invN;
    else if (i < 512) v = unfkey(maxkey[i-256]);
    else              v = att_raw[i-512]*invS;
    comb[i] = v;
  }
  __syncthreads();
  { int n = t&127, part = t>>7;
    float a = 0.f;
    for (int f=part*192; f<part*192+192; f++) a += comb[f]*Wm1[f*128+n];
    z1p[part][n] = a;
  }
  __syncthreads();
  if (t < 128)
    z1[t] = fmaxf(bm1[t] + z1p[0][t]+z1p[1][t]+z1p[2][t]+z1p[3][t], 0.f);
  __syncthreads();
  { int n = t&63, part = t>>6;
    float a = 0.f;
    for (int f=part*16; f<part*16+16; f++) a += z1[f]*Wm2[f*64+n];
    z2p[part][n] = a;
  }
  __syncthreads();
  if (t < 64){
    float a = bm2[t];
    #pragma unroll
    for (int p=0;p<8;p++) a += z2p[p][t];
    z2[t] = fmaxf(a, 0.f);
  }
  __syncthreads();
  { int n = t&127, part = t>>7;
    float a = 0.f;
    for (int f=part*16; f<part*16+16; f++) a += z2[f]*Wm3[f*128+n];
    z3p[part][n] = a;
  }
  __syncthreads();
  if (t < 128)
    out[t] = bm3[t] + z3p[0][t]+z3p[1][t]+z3p[2][t]+z3p[3][t];
}

extern "C" void kernel_launch(void* const* d_in, const int* in_sizes, int n_in,
                              void* d_out, int out_size, void* d_ws, size_t ws_size,
                              hipStream_t stream){
  (void)in_sizes; (void)n_in; (void)out_size; (void)ws_size;
  const float* x   = (const float*)d_in[0];
  const int*   ei  = (const int*)d_in[1];
  const float* ea  = (const float*)d_in[2];
  const float* W0  = (const float*)d_in[3];
  const float* as0 = (const float*)d_in[4];
  const float* ad0 = (const float*)d_in[5];
  const float* We0 = (const float*)d_in[6];
  const float* ae0 = (const float*)d_in[7];
  const float* b0  = (const float*)d_in[8];
  const float* W1  = (const float*)d_in[9];
  const float* as1 = (const float*)d_in[10];
  const float* ad1 = (const float*)d_in[11];
  const float* We1 = (const float*)d_in[12];
  const float* ae1 = (const float*)d_in[13];
  const float* b1  = (const float*)d_in[14];
  const float* Wm1 = (const float*)d_in[15];
  const float* bm1 = (const float*)d_in[16];
  const float* Wm2 = (const float*)d_in[17];
  const float* bm2 = (const float*)d_in[18];
  const float* Wm3 = (const float*)d_in[19];
  const float* bm3 = (const float*)d_in[20];
  float* out = (float*)d_out;

  char* ws = (char*)d_ws;
  size_t o = 0;
  auto alloc = [&](size_t bytes)->size_t{
    size_t r = o; o = (o + bytes + 255) & ~(size_t)255; return r;
  };
  size_t o_bufF   = alloc((size_t)N_*256*4);   // x1 (fp32), then h2 (fp16)
  size_t o_bufH   = alloc((size_t)N_*256*2);   // h0, then h1 (fp16)
  size_t o_als0   = alloc((size_t)N_*4*4);
  size_t o_ald0   = alloc((size_t)N_*4*4);
  size_t o_als1   = alloc((size_t)N_*4*4);
  size_t o_ald1   = alloc((size_t)N_*4*4);
  size_t o_rowptr = alloc((size_t)(N_+1)*4);
  size_t o_csr2   = alloc((size_t)E_*8);       // int2 (src,dst)
  size_t o_pe     = alloc((size_t)E_*16);      // uint4: p0 x4 fp16 | ale1 x4 fp16
  size_t o_p1     = alloc((size_t)E_*4*2);     // fp16 x4 per edge (layer-1 p)
  size_t o_rank   = alloc((size_t)E_);         // uchar rank within (copy,dst)
  size_t o_base   = alloc((size_t)NCOPY*N_*4); // per-copy CSR bases
  size_t o_Bhi    = alloc((size_t)256*256*2);
  size_t o_Blo    = alloc((size_t)256*256*2);
  size_t o_bsum   = alloc(256*4);
  size_t o_bpre   = alloc(256*4);
  size_t o_eapart = alloc(256*4*4);
  // --- zero block ---
  size_t zstart   = o;
  size_t o_deg8   = alloc((size_t)NCOPY*N_*4);
  size_t o_sumpool= alloc(256*4);
  size_t o_maxkey = alloc(256*4);
  size_t o_attraw = alloc(256*4);
  size_t o_ssum   = alloc(4);
  size_t zend     = o;
  size_t o_small  = alloc(40*4);

  float*  bufF   = (float*)(ws + o_bufF);
  __half* bufH   = (__half*)(ws + o_bufH);
  __half* h2h    = (__half*)(ws + o_bufF);     // reuse bufF region for fp16 h2
  float* pals0  = (float*)(ws + o_als0);
  float* pald0  = (float*)(ws + o_ald0);
  float* pals1  = (float*)(ws + o_als1);
  float* pald1  = (float*)(ws + o_ald1);
  int*   rowptr = (int*)(ws + o_rowptr);
  int2*  csr2   = (int2*)(ws + o_csr2);
  uint4* pe     = (uint4*)(ws + o_pe);
  __half* p1h   = (__half*)(ws + o_p1);
  unsigned char* rank = (unsigned char*)(ws + o_rank);
  int*   base   = (int*)(ws + o_base);
  ushort* Bhi   = (ushort*)(ws + o_Bhi);
  ushort* Blo   = (ushort*)(ws + o_Blo);
  int*   bsum   = (int*)(ws + o_bsum);
  int*   bpre   = (int*)(ws + o_bpre);
  float* eapart = (float*)(ws + o_eapart);
  int*   deg8   = (int*)(ws + o_deg8);
  float* sumpool= (float*)(ws + o_sumpool);
  unsigned* maxkey = (unsigned*)(ws + o_maxkey);
  float* attraw = (float*)(ws + o_attraw);
  float* ssum   = (float*)(ws + o_ssum);
  float* small  = (float*)(ws + o_small);

  hipMemsetAsync(ws + zstart, 0, zend - zstart, stream);

  int eb = (int)((E_ + 255)/256);          // 3125
  int nb_wave = (int)((N_*64 + 255)/256);  // 12500 (one wave per node)
  int gb = (int)((N_ + 31)/32);            // 1563 gemm blocks
  int sb = (int)((N_ + 255)/256);          // 196 scan blocks

  k_pre    <<<eb, 256, 0, stream>>>(ei, deg8, rank, W1, Bhi, Blo);
  k_scan1  <<<sb, 256, 0, stream>>>(deg8, bsum, ea, eapart);
  k_scan2  <<<1, 256, 0, stream>>>(bsum, bpre, sb, rowptr,
                                   We0, ae0, We1, ae1, eapart, small);
  k_scan3  <<<sb, 256, 0, stream>>>(deg8, bpre, rowptr, base);
  k_h0     <<<nb_wave, 256, 0, stream>>>(x, W0, as0, ad0, bufH, pals0, pald0);
  k_scatter<<<eb, 256, 0, stream>>>(ei, ea, base, rank, csr2, pe,
                                    small, pals0, pald0);
  k_agg<float,true>  <<<nb_wave, 256, 0, stream>>>(bufH, pals0, pald0, rowptr, csr2,
                                         (const __half*)pe, 8, small, 32, b0, bufF);
  k_gemm   <<<gb, 256, 0, stream>>>(bufF, Bhi, Blo, bufH, as1, ad1, pals1, pald1);
  k_palpha1<<<eb, 256, 0, stream>>>(csr2, pe, pals1, pald1, p1h);
  k_agg<__half,false><<<nb_wave, 256, 0, stream>>>(bufH, pals1, pald1, rowptr, csr2,
                                         p1h, 4, small, 36, b1, h2h);
  k_pool1  <<<256, 256, 0, stream>>>(h2h, sumpool, maxkey);
  k_atts   <<<256, 256, 0, stream>>>(h2h, sumpool, ssum, attraw);
  k_mlp    <<<1, 512, 0, stream>>>(sumpool, maxkey, attraw, ssum,
                                   Wm1, bm1, Wm2, bm2, Wm3, bm3, out);
}

// Round 8
// 493.995 us; speedup vs baseline: 1.1524x; 1.0018x over previous
//
#include <hip/hip_runtime.h>
#include <hip/hip_fp16.h>
#include <type_traits>

static const long long N_ = 50000;
static const long long E_ = 800000;
static const int NCOPY = 8;
#define LOG2E 1.44269504088896f

typedef __attribute__((ext_vector_type(8))) short bf16x8;
typedef __attribute__((ext_vector_type(4))) float f32x4;

__device__ __forceinline__ float lrelu(float x){ return x >= 0.f ? x : 0.2f*x; }
__device__ __forceinline__ unsigned fkey(float x){
  unsigned u = __float_as_uint(x);
  return (u & 0x80000000u) ? ~u : (u | 0x80000000u);
}
__device__ __forceinline__ float unfkey(unsigned k){
  return __uint_as_float((k & 0x80000000u) ? (k & 0x7fffffffu) : ~k);
}
__device__ __forceinline__ unsigned h2u(__half2 h){ return *(unsigned*)&h; }

// ---- fused prologue: deg histogram (+rank) + W1 prep + h0 GEMV (K=5) ----
// h0's VALU work hides under the histogram's atomic latency (k_pre was 1% VALUBusy).
__global__ void k_pre(const int* __restrict__ ei, int* __restrict__ deg8,
                      unsigned char* __restrict__ rank,
                      const float* __restrict__ W1, ushort* __restrict__ Bhi,
                      ushort* __restrict__ Blo,
                      const float* __restrict__ x, const float* __restrict__ W0,
                      const float* __restrict__ as0, const float* __restrict__ ad0,
                      __half* __restrict__ h0, float* __restrict__ als,
                      float* __restrict__ ald){
  int t = threadIdx.x;
  long long e = (long long)blockIdx.x*256 + t;
  if (e < E_){
    int d = ei[E_ + e];
    int copy = blockIdx.x & (NCOPY-1);
    int old = atomicAdd(&deg8[copy*(int)N_ + d], 1);
    rank[e] = (unsigned char)old;
  }
  if (blockIdx.x < 256){
    int k = blockIdx.x, n = t;
    float v = W1[k*256+n];
    unsigned u = __float_as_uint(v);
    ushort hi = (ushort)(u>>16);
    float rem = v - __uint_as_float(u & 0xffff0000u);
    unsigned ur = __float_as_uint(rem);
    ushort lo = (ushort)((ur + 0x7fff + ((ur>>16)&1)) >> 16);
    int tl = n>>4, kb = k>>5, q = (k>>3)&3, j = k&7;
    long long idx = ((((long long)tl*8+kb)*64 + q*16 + (n&15))<<3) + j;
    Bhi[idx] = hi; Blo[idx] = lo;
  }
  // ---- h0: 16 nodes per block (3125*16 = 50000 exactly), one wave per node x4 ----
  int w = t>>6, lane = t&63;
  int c = lane*4, head = lane>>4;
  #pragma unroll
  for (int rep=0; rep<4; rep++){
    int wid = blockIdx.x*16 + w*4 + rep;
    if (wid >= (int)N_) break;
    const float* xr = x + wid*5;
    float xv[5];
    #pragma unroll
    for (int f=0; f<5; f++) xv[f] = xr[f];
    float a0=0,a1=0,a2=0,a3=0;
    #pragma unroll
    for (int f=0; f<5; f++){
      const float* wr = W0 + f*256 + c;
      a0 += xv[f]*wr[0]; a1 += xv[f]*wr[1]; a2 += xv[f]*wr[2]; a3 += xv[f]*wr[3];
    }
    uint2 pk = make_uint2(h2u(__floats2half2_rn(a0,a1)), h2u(__floats2half2_rn(a2,a3)));
    *(uint2*)(h0 + (long long)wid*256 + c) = pk;
    const float* asp = as0 + c;
    const float* adp = ad0 + c;
    float ss = a0*asp[0]+a1*asp[1]+a2*asp[2]+a3*asp[3];
    float dd = a0*adp[0]+a1*adp[1]+a2*adp[2]+a3*adp[3];
    #pragma unroll
    for (int m=1; m<16; m<<=1){ ss += __shfl_xor(ss, m); dd += __shfl_xor(dd, m); }
    if ((lane&15)==0){ als[wid*4+head]=ss*LOG2E; ald[wid*4+head]=dd*LOG2E; }
  }
}

// ---- scan phase 1: per-block sums of total deg + ea column partial sums ----
__global__ void k_scan1(const int* __restrict__ deg8, int* __restrict__ bsum,
                        const float* __restrict__ ea, float* __restrict__ eapart){
  __shared__ int lds[256];
  __shared__ float fl[256];
  int t = threadIdx.x;
  long long idx = (long long)blockIdx.x*256 + t;
  int v = 0;
  if (idx < N_){
    #pragma unroll
    for (int c=0;c<NCOPY;c++) v += deg8[c*(int)N_ + idx];
  }
  lds[t] = v;
  float s = 0.f;
  for (long long i = (long long)blockIdx.x*256 + t; i < E_*4; i += (long long)gridDim.x*256)
    s += ea[i];
  fl[t] = s;
  __syncthreads();
  for (int st=128; st>=1; st>>=1){
    if (t<st) lds[t] += lds[t+st];
    if (t<st && st>=4) fl[t] += fl[t+st];
    __syncthreads();
  }
  if (t==0) bsum[blockIdx.x] = lds[0];
  if (t<4) eapart[blockIdx.x*4 + t] = fl[t];
}

// ---- phase 2: scan block sums + fused "small" precompute (log2-scaled) ----
// small layout: [0..15]=Ae0*log2e, [16..31]=Ae1*log2e, [32..35]=loop0, [36..39]=loop1
__global__ void k_scan2(const int* __restrict__ bsum, int* __restrict__ bpre, int nb,
                        int* __restrict__ rowptr,
                        const float* __restrict__ We0, const float* __restrict__ ae0,
                        const float* __restrict__ We1, const float* __restrict__ ae1,
                        const float* __restrict__ eapart, float* __restrict__ small){
  __shared__ int lds[256];
  __shared__ float sea[4];
  int t = threadIdx.x;
  int v = (t < nb) ? bsum[t] : 0;
  lds[t] = v; __syncthreads();
  for (int off=1; off<256; off<<=1){
    int add = (t>=off) ? lds[t-off] : 0;
    __syncthreads();
    lds[t] += add;
    __syncthreads();
  }
  if (t < nb) bpre[t] = lds[t] - v;     // exclusive
  if (t == 0) rowptr[N_] = (int)E_;
  if (t < 4){
    float s = 0.f;
    for (int b=0;b<nb;b++) s += eapart[b*4+t];
    sea[t] = s;
  }
  if (t < 32){
    int l = t>>4, f = (t>>2)&3, h = t&3;
    const float* We = l ? We1 : We0;
    const float* ae = l ? ae1 : ae0;
    float s = 0.f;
    for (int cc=0; cc<64; cc++) s += We[f*256 + h*64 + cc]*ae[h*64+cc];
    small[l*16 + f*4 + h] = s * LOG2E;
  }
  __syncthreads();
  if (t < 8){
    int l = t>>2, h = t&3;
    const float* Ae = small + l*16;       // already scaled
    const float invE = 1.f/(float)E_;
    float s = 0.f;
    for (int f=0; f<4; f++) s += sea[f]*invE*Ae[f*4+h];
    small[32 + l*4 + h] = s;
  }
}

// ---- phase 3: local scan + block offset -> rowptr + per-copy bases ----
__global__ void k_scan3(const int* __restrict__ deg8, const int* __restrict__ bpre,
                        int* __restrict__ rowptr, int* __restrict__ base){
  __shared__ int lds[256];
  int t = threadIdx.x;
  long long idx = (long long)blockIdx.x*256 + t;
  int dd[NCOPY]; int v = 0;
  if (idx < N_){
    #pragma unroll
    for (int c=0;c<NCOPY;c++){ dd[c] = deg8[c*(int)N_ + idx]; v += dd[c]; }
  }
  lds[t] = v; __syncthreads();
  for (int off=1; off<256; off<<=1){
    int add = (t>=off) ? lds[t-off] : 0;
    __syncthreads();
    lds[t] += add;
    __syncthreads();
  }
  if (idx < N_){
    int rp = bpre[blockIdx.x] + lds[t] - v;
    rowptr[idx] = rp;
    int cum = rp;
    #pragma unroll
    for (int c=0;c<NCOPY;c++){ base[c*(int)N_ + idx] = cum; cum += dd[c]; }
  }
}

// ---- scatter (atomic-free): pos = base[copy][d] + rank[e]; fused p0 + ale1 ----
__global__ void k_scatter(const int* __restrict__ ei, const float* __restrict__ ea,
                          const int* __restrict__ base, const unsigned char* __restrict__ rank,
                          int* __restrict__ csrs, uint4* __restrict__ pe,
                          const float* __restrict__ small,
                          const float* __restrict__ als0, const float* __restrict__ ald0){
  long long e = (long long)blockIdx.x*256 + threadIdx.x;
  if (e >= E_) return;
  int s = ei[e], d = ei[E_+e];
  int copy = blockIdx.x & (NCOPY-1);
  int pos = base[copy*(int)N_ + d] + (int)rank[e];
  csrs[pos] = s;
  float4 v = *(const float4*)(ea + e*4);
  float4 As = *(const float4*)(als0 + s*4);
  float4 Ad = *(const float4*)(ald0 + d*4);
  float as_[4] = {As.x,As.y,As.z,As.w};
  float ad_[4] = {Ad.x,Ad.y,Ad.z,Ad.w};
  float p0[4], o1[4];
  #pragma unroll
  for (int h=0; h<4; h++){
    float a0 = v.x*small[0+h]  + v.y*small[4+h]  + v.z*small[8+h]  + v.w*small[12+h];
    p0[h] = exp2f(lrelu(as_[h] + ad_[h] + a0));
    o1[h] = v.x*small[16+h] + v.y*small[20+h] + v.z*small[24+h] + v.w*small[28+h];
  }
  uint4 pk = make_uint4(h2u(__floats2half2_rn(p0[0],p0[1])),
                        h2u(__floats2half2_rn(p0[2],p0[3])),
                        h2u(__floats2half2_rn(o1[0],o1[1])),
                        h2u(__floats2half2_rn(o1[2],o1[3])));
  pe[pos] = pk;
}

// ---- GAT aggregation: one wave/node; 2 edges/wave (16B/lane), 6-pair unroll.
// INLINE_P: p = exp2(lrelu(als[s]+ald[wid]+ale)) computed in-loop (layer 1);
// otherwise p is read precomputed from pe (layer 0).
template<typename OutT, bool RELU, bool INLINE_P>
__global__ __launch_bounds__(256) void k_agg(const __half* __restrict__ hin,
    const float* __restrict__ als, const float* __restrict__ ald,
    const int* __restrict__ rowptr, const int* __restrict__ csrs,
    const __half* __restrict__ ph, int pstride, int poff,
    const float* __restrict__ small, int loop_off,
    const float* __restrict__ bias, OutT* __restrict__ out){
  int wid = (int)(((long long)blockIdx.x*256 + threadIdx.x) >> 6);
  int lane = threadIdx.x & 63;
  if (wid >= (int)N_) return;
  int half_ = lane>>5, l5 = lane&31;
  int head = l5>>3, c8 = l5*8;
  const uint4* hp = (const uint4*)hin;
  float aldv = ald[wid*4+head];
  float a[8]; float den;
  // self-loop (lower half only; upper half starts empty)
  {
    float pS = exp2f(lrelu(als[wid*4+head] + aldv + small[loop_off+head]));
    float pp = (half_==0) ? pS : 0.f;
    uint4 r = hp[wid*32 + l5];
    float2 f0 = __half22float2(*(__half2*)&r.x);
    float2 f1 = __half22float2(*(__half2*)&r.y);
    float2 f2 = __half22float2(*(__half2*)&r.z);
    float2 f3 = __half22float2(*(__half2*)&r.w);
    den = pp;
    a[0]=pp*f0.x; a[1]=pp*f0.y; a[2]=pp*f1.x; a[3]=pp*f1.y;
    a[4]=pp*f2.x; a[5]=pp*f2.y; a[6]=pp*f3.x; a[7]=pp*f3.y;
  }
  int beg = rowptr[wid], end = rowptr[wid+1];
  int i = beg;
  const int UN = 6;
  for (; i + 2*UN-1 < end; i += 2*UN){
    int sv[UN]; float pv[UN]; uint4 rr[UN];
    #pragma unroll
    for (int k=0;k<UN;k++) sv[k] = csrs[i + 2*k + half_];
    #pragma unroll
    for (int k=0;k<UN;k++) rr[k] = hp[sv[k]*32 + l5];     // big gathers first
    #pragma unroll
    for (int k=0;k<UN;k++){
      int e = i + 2*k + half_;
      if (INLINE_P){
        float alev = __half2float(ph[e*pstride + poff + head]);
        float alsv = als[sv[k]*4 + head];
        pv[k] = exp2f(lrelu(alsv + aldv + alev));
      } else {
        pv[k] = __half2float(ph[e*pstride + poff + head]);
      }
    }
    #pragma unroll
    for (int k=0;k<UN;k++){
      float2 f0 = __half22float2(*(__half2*)&rr[k].x);
      float2 f1 = __half22float2(*(__half2*)&rr[k].y);
      float2 f2 = __half22float2(*(__half2*)&rr[k].z);
      float2 f3 = __half22float2(*(__half2*)&rr[k].w);
      float p = pv[k];
      den += p;
      a[0]+=p*f0.x; a[1]+=p*f0.y; a[2]+=p*f1.x; a[3]+=p*f1.y;
      a[4]+=p*f2.x; a[5]+=p*f2.y; a[6]+=p*f3.x; a[7]+=p*f3.y;
    }
  }
  for (; i < end; i += 2){
    int e = i + half_;
    bool act = (e < end);
    int ee = act ? e : (end-1);
    int s0 = csrs[ee];
    float p;
    if (INLINE_P){
      float alev = __half2float(ph[ee*pstride + poff + head]);
      float alsv = als[s0*4 + head];
      p = exp2f(lrelu(alsv + aldv + alev));
    } else {
      p = __half2float(ph[ee*pstride + poff + head]);
    }
    if (!act) p = 0.f;
    uint4 r = hp[s0*32 + l5];
    float2 f0 = __half22float2(*(__half2*)&r.x);
    float2 f1 = __half22float2(*(__half2*)&r.y);
    float2 f2 = __half22float2(*(__half2*)&r.z);
    float2 f3 = __half22float2(*(__half2*)&r.w);
    den += p;
    a[0]+=p*f0.x; a[1]+=p*f0.y; a[2]+=p*f1.x; a[3]+=p*f1.y;
    a[4]+=p*f2.x; a[5]+=p*f2.y; a[6]+=p*f3.x; a[7]+=p*f3.y;
  }
  // merge halves
  den += __shfl_xor(den, 32);
  #pragma unroll
  for (int j=0;j<8;j++) a[j] += __shfl_xor(a[j], 32);
  if (half_ == 0){
    float inv = 1.f/(den + 1e-16f);
    float4 b0 = *(const float4*)(bias + c8);
    float4 b1 = *(const float4*)(bias + c8 + 4);
    float o[8];
    o[0]=a[0]*inv+b0.x; o[1]=a[1]*inv+b0.y; o[2]=a[2]*inv+b0.z; o[3]=a[3]*inv+b0.w;
    o[4]=a[4]*inv+b1.x; o[5]=a[5]*inv+b1.y; o[6]=a[6]*inv+b1.z; o[7]=a[7]*inv+b1.w;
    if (RELU){
      #pragma unroll
      for (int j=0;j<8;j++) o[j] = fmaxf(o[j], 0.f);
    }
    if constexpr (std::is_same<OutT,__half>::value){
      uint4 qk = make_uint4(h2u(__floats2half2_rn(o[0],o[1])), h2u(__floats2half2_rn(o[2],o[3])),
                            h2u(__floats2half2_rn(o[4],o[5])), h2u(__floats2half2_rn(o[6],o[7])));
      *(uint4*)(out + (long long)wid*256 + c8) = qk;
    } else {
      *(float4*)(out + (long long)wid*256 + c8)     = make_float4(o[0],o[1],o[2],o[3]);
      *(float4*)(out + (long long)wid*256 + c8 + 4) = make_float4(o[4],o[5],o[6],o[7]);
    }
  }
}

// ---- h1 = x1 @ W1 via split-bf16 MFMA (3 products); fp16 out; fused als1/ald1 ----
__global__ __launch_bounds__(256) void k_gemm(const float* __restrict__ A,
    const ushort* __restrict__ Bhi, const ushort* __restrict__ Blo,
    __half* __restrict__ Ch, const float* __restrict__ as1, const float* __restrict__ ad1,
    float* __restrict__ als, float* __restrict__ ald){
  __shared__ ushort Ah[32*264];
  __shared__ ushort Al[32*264];
  int t = threadIdx.x;
  long long base = (long long)blockIdx.x*32;
  for (int i=t; i<2048; i+=256){
    int r = i>>6, q4 = i&63;
    float4 v = make_float4(0.f,0.f,0.f,0.f);
    if (base + r < N_) v = *(const float4*)(A + (base+r)*256 + q4*4);
    float vv[4] = {v.x,v.y,v.z,v.w};
    ushort hh[4], ll[4];
    #pragma unroll
    for (int e=0;e<4;e++){
      unsigned u = __float_as_uint(vv[e]);
      hh[e] = (ushort)(u>>16);
      float rem = vv[e] - __uint_as_float(u & 0xffff0000u);
      unsigned ur = __float_as_uint(rem);
      ll[e] = (ushort)((ur + 0x7fff + ((ur>>16)&1)) >> 16);
    }
    int off = r*264 + q4*4;
    *(ushort4*)(Ah+off) = make_ushort4(hh[0],hh[1],hh[2],hh[3]);
    *(ushort4*)(Al+off) = make_ushort4(ll[0],ll[1],ll[2],ll[3]);
  }
  __syncthreads();
  int w = t>>6, lane = t&63, m = lane&15, q = lane>>4;
  int rbase = (w>>1)*16;
  int nhalf = (w&1)*8;
  f32x4 acc[8];
  #pragma unroll
  for (int i=0;i<8;i++) acc[i] = (f32x4){0.f,0.f,0.f,0.f};
  for (int kb=0; kb<8; kb++){
    int aoff = (rbase+m)*264 + kb*32 + q*8;
    bf16x8 ah = *(const bf16x8*)(Ah + aoff);
    bf16x8 al = *(const bf16x8*)(Al + aoff);
    #pragma unroll
    for (int tt=0; tt<8; tt++){
      long long bidx = ((((long long)(nhalf+tt)*8+kb)*64 + lane)<<3);
      bf16x8 bh = *(const bf16x8*)(Bhi + bidx);
      bf16x8 bl = *(const bf16x8*)(Blo + bidx);
      acc[tt] = __builtin_amdgcn_mfma_f32_16x16x32_bf16(ah, bh, acc[tt], 0,0,0);
      acc[tt] = __builtin_amdgcn_mfma_f32_16x16x32_bf16(al, bh, acc[tt], 0,0,0);
      acc[tt] = __builtin_amdgcn_mfma_f32_16x16x32_bf16(ah, bl, acc[tt], 0,0,0);
    }
  }
  float ssv[4][2], ddv[4][2];
  #pragma unroll
  for (int r=0;r<4;r++){ ssv[r][0]=0.f; ssv[r][1]=0.f; ddv[r][0]=0.f; ddv[r][1]=0.f; }
  #pragma unroll
  for (int tt=0; tt<8; tt++){
    int col = (nhalf+tt)*16 + m;
    float as_ = as1[col], ad_ = ad1[col];
    int hh = tt>>2;
    #pragma unroll
    for (int r=0;r<4;r++){
      ssv[r][hh] += acc[tt][r]*as_;
      ddv[r][hh] += acc[tt][r]*ad_;
    }
  }
  #pragma unroll
  for (int r=0;r<4;r++){
    #pragma unroll
    for (int hh=0; hh<2; hh++){
      #pragma unroll
      for (int mm=1; mm<16; mm<<=1){
        ssv[r][hh] += __shfl_xor(ssv[r][hh], mm);
        ddv[r][hh] += __shfl_xor(ddv[r][hh], mm);
      }
    }
  }
  #pragma unroll
  for (int r=0;r<4;r++){
    long long grow = base + rbase + q*4 + r;
    if (grow < N_){
      #pragma unroll
      for (int tt=0; tt<8; tt++)
        Ch[grow*256 + (nhalf+tt)*16 + m] = __float2half(acc[tt][r]);
      if (m==0){
        int hb = (w&1)*2;
        als[grow*4 + hb+0] = ssv[r][0]*LOG2E;
        ald[grow*4 + hb+0] = ddv[r][0]*LOG2E;
        als[grow*4 + hb+1] = ssv[r][1]*LOG2E;
        ald[grow*4 + hb+1] = ddv[r][1]*LOG2E;
      }
    }
  }
}

// ---- column-wise sum & max over nodes (fp16 h2) ----
__global__ void k_pool1(const __half* __restrict__ h2, float* __restrict__ sum_pool,
                        unsigned* __restrict__ maxkey){
  int c = threadIdx.x; // 256
  float s = 0.f; float m = -3.4e38f;
  for (long long n = blockIdx.x; n < N_; n += gridDim.x){
    float v = __half2float(h2[n*256+c]); s += v; m = fmaxf(m, v);
  }
  atomicAdd(&sum_pool[c], s);
  atomicMax(&maxkey[c], fkey(m));
}

// ---- fused attention pool: s[n]=dot(h2[n],mp); accumulate ssum & att_raw ----
__global__ void k_atts(const __half* __restrict__ h2, const float* __restrict__ sum_pool,
                       float* __restrict__ ssum, float* __restrict__ att_raw){
  __shared__ float part[4][256];
  __shared__ float es[4];
  int t = threadIdx.x; int lane = t&63; int w = t>>6;
  const float invN = 1.f/(float)N_;
  int c = lane*4;
  float4 mp = *(const float4*)(sum_pool + c);
  float esum = 0.f;
  float acc0=0.f, acc1=0.f, acc2=0.f, acc3=0.f;
  for (long long wid = (long long)blockIdx.x*4 + w; wid < N_; wid += (long long)gridDim.x*4){
    uint2 pk = *(const uint2*)(h2 + wid*256 + c);
    float2 a01 = __half22float2(*(__half2*)&pk.x);
    float2 a23 = __half22float2(*(__half2*)&pk.y);
    float s = (a01.x*mp.x + a01.y*mp.y + a23.x*mp.z + a23.y*mp.w)*invN;
    #pragma unroll
    for (int m=1; m<64; m<<=1) s += __shfl_xor(s, m);
    float e = __expf(s);
    if (lane==0) esum += e;
    acc0 += e*a01.x; acc1 += e*a01.y; acc2 += e*a23.x; acc3 += e*a23.y;
  }
  part[w][c+0]=acc0; part[w][c+1]=acc1; part[w][c+2]=acc2; part[w][c+3]=acc3;
  if (lane==0) es[w] = esum;
  __syncthreads();
  if (t < 256){
    float v = part[0][t]+part[1][t]+part[2][t]+part[3][t];
    atomicAdd(&att_raw[t], v);
  }
  if (t==0) atomicAdd(ssum, es[0]+es[1]+es[2]+es[3]);
}

// ---- final MLP: [768] -> 128 -> 64 -> 128, split-K across 512 threads ----
__global__ void k_mlp(const float* __restrict__ sum_pool, const unsigned* __restrict__ maxkey,
                      const float* __restrict__ att_raw, const float* __restrict__ ssum,
                      const float* __restrict__ Wm1, const float* __restrict__ bm1,
                      const float* __restrict__ Wm2, const float* __restrict__ bm2,
                      const float* __restrict__ Wm3, const float* __restrict__ bm3,
                      float* __restrict__ out){
  __shared__ float comb[768];
  __shared__ float z1p[4][128]; __shared__ float z1[128];
  __shared__ float z2p[8][64];  __shared__ float z2[64];
  __shared__ float z3p[4][128];
  int t = threadIdx.x; // 512
  const float invN = 1.f/(float)N_;
  float invS = 1.f/(*ssum);
  for (int i=t; i<768; i+=512){
    float v;
    if (i < 256)      v = sum_pool[i]*invN;
    else if (i < 512) v = unfkey(maxkey[i-256]);
    else              v = att_raw[i-512]*invS;
    comb[i] = v;
  }
  __syncthreads();
  { int n = t&127, part = t>>7;
    float a = 0.f;
    for (int f=part*192; f<part*192+192; f++) a += comb[f]*Wm1[f*128+n];
    z1p[part][n] = a;
  }
  __syncthreads();
  if (t < 128)
    z1[t] = fmaxf(bm1[t] + z1p[0][t]+z1p[1][t]+z1p[2][t]+z1p[3][t], 0.f);
  __syncthreads();
  { int n = t&63, part = t>>6;
    float a = 0.f;
    for (int f=part*16; f<part*16+16; f++) a += z1[f]*Wm2[f*64+n];
    z2p[part][n] = a;
  }
  __syncthreads();
  if (t < 64){
    float a = bm2[t];
    #pragma unroll
    for (int p=0;p<8;p++) a += z2p[p][t];
    z2[t] = fmaxf(a, 0.f);
  }
  __syncthreads();
  { int n = t&127, part = t>>7;
    float a = 0.f;
    for (int f=part*16; f<part*16+16; f++) a += z2[f]*Wm3[f*128+n];
    z3p[part][n] = a;
  }
  __syncthreads();
  if (t < 128)
    out[t] = bm3[t] + z3p[0][t]+z3p[1][t]+z3p[2][t]+z3p[3][t];
}

extern "C" void kernel_launch(void* const* d_in, const int* in_sizes, int n_in,
                              void* d_out, int out_size, void* d_ws, size_t ws_size,
                              hipStream_t stream){
  (void)in_sizes; (void)n_in; (void)out_size; (void)ws_size;
  const float* x   = (const float*)d_in[0];
  const int*   ei  = (const int*)d_in[1];
  const float* ea  = (const float*)d_in[2];
  const float* W0  = (const float*)d_in[3];
  const float* as0 = (const float*)d_in[4];
  const float* ad0 = (const float*)d_in[5];
  const float* We0 = (const float*)d_in[6];
  const float* ae0 = (const float*)d_in[7];
  const float* b0  = (const float*)d_in[8];
  const float* W1  = (const float*)d_in[9];
  const float* as1 = (const float*)d_in[10];
  const float* ad1 = (const float*)d_in[11];
  const float* We1 = (const float*)d_in[12];
  const float* ae1 = (const float*)d_in[13];
  const float* b1  = (const float*)d_in[14];
  const float* Wm1 = (const float*)d_in[15];
  const float* bm1 = (const float*)d_in[16];
  const float* Wm2 = (const float*)d_in[17];
  const float* bm2 = (const float*)d_in[18];
  const float* Wm3 = (const float*)d_in[19];
  const float* bm3 = (const float*)d_in[20];
  float* out = (float*)d_out;

  char* ws = (char*)d_ws;
  size_t o = 0;
  auto alloc = [&](size_t bytes)->size_t{
    size_t r = o; o = (o + bytes + 255) & ~(size_t)255; return r;
  };
  size_t o_bufF   = alloc((size_t)N_*256*4);   // x1 (fp32), then h2 (fp16)
  size_t o_bufH   = alloc((size_t)N_*256*2);   // h0, then h1 (fp16)
  size_t o_als0   = alloc((size_t)N_*4*4);
  size_t o_ald0   = alloc((size_t)N_*4*4);
  size_t o_als1   = alloc((size_t)N_*4*4);
  size_t o_ald1   = alloc((size_t)N_*4*4);
  size_t o_rowptr = alloc((size_t)(N_+1)*4);
  size_t o_csrs   = alloc((size_t)E_*4);       // src only
  size_t o_pe     = alloc((size_t)E_*16);      // uint4: p0 x4 fp16 | ale1 x4 fp16
  size_t o_rank   = alloc((size_t)E_);         // uchar rank within (copy,dst)
  size_t o_base   = alloc((size_t)NCOPY*N_*4); // per-copy CSR bases
  size_t o_Bhi    = alloc((size_t)256*256*2);
  size_t o_Blo    = alloc((size_t)256*256*2);
  size_t o_bsum   = alloc(256*4);
  size_t o_bpre   = alloc(256*4);
  size_t o_eapart = alloc(256*4*4);
  // --- zero block ---
  size_t zstart   = o;
  size_t o_deg8   = alloc((size_t)NCOPY*N_*4);
  size_t o_sumpool= alloc(256*4);
  size_t o_maxkey = alloc(256*4);
  size_t o_attraw = alloc(256*4);
  size_t o_ssum   = alloc(4);
  size_t zend     = o;
  size_t o_small  = alloc(40*4);

  float*  bufF   = (float*)(ws + o_bufF);
  __half* bufH   = (__half*)(ws + o_bufH);
  __half* h2h    = (__half*)(ws + o_bufF);     // reuse bufF region for fp16 h2
  float* pals0  = (float*)(ws + o_als0);
  float* pald0  = (float*)(ws + o_ald0);
  float* pals1  = (float*)(ws + o_als1);
  float* pald1  = (float*)(ws + o_ald1);
  int*   rowptr = (int*)(ws + o_rowptr);
  int*   csrs   = (int*)(ws + o_csrs);
  uint4* pe     = (uint4*)(ws + o_pe);
  unsigned char* rank = (unsigned char*)(ws + o_rank);
  int*   base   = (int*)(ws + o_base);
  ushort* Bhi   = (ushort*)(ws + o_Bhi);
  ushort* Blo   = (ushort*)(ws + o_Blo);
  int*   bsum   = (int*)(ws + o_bsum);
  int*   bpre   = (int*)(ws + o_bpre);
  float* eapart = (float*)(ws + o_eapart);
  int*   deg8   = (int*)(ws + o_deg8);
  float* sumpool= (float*)(ws + o_sumpool);
  unsigned* maxkey = (unsigned*)(ws + o_maxkey);
  float* attraw = (float*)(ws + o_attraw);
  float* ssum   = (float*)(ws + o_ssum);
  float* small  = (float*)(ws + o_small);

  hipMemsetAsync(ws + zstart, 0, zend - zstart, stream);

  int eb = (int)((E_ + 255)/256);          // 3125
  int nb_wave = (int)((N_*64 + 255)/256);  // 12500 (one wave per node)
  int gb = (int)((N_ + 31)/32);            // 1563 gemm blocks
  int sb = (int)((N_ + 255)/256);          // 196 scan blocks

  k_pre    <<<eb, 256, 0, stream>>>(ei, deg8, rank, W1, Bhi, Blo,
                                    x, W0, as0, ad0, bufH, pals0, pald0);
  k_scan1  <<<sb, 256, 0, stream>>>(deg8, bsum, ea, eapart);
  k_scan2  <<<1, 256, 0, stream>>>(bsum, bpre, sb, rowptr,
                                   We0, ae0, We1, ae1, eapart, small);
  k_scan3  <<<sb, 256, 0, stream>>>(deg8, bpre, rowptr, base);
  k_scatter<<<eb, 256, 0, stream>>>(ei, ea, base, rank, csrs, pe,
                                    small, pals0, pald0);
  k_agg<float,true,false> <<<nb_wave, 256, 0, stream>>>(bufH, pals0, pald0, rowptr, csrs,
                                         (const __half*)pe, 8, 0, small, 32, b0, bufF);
  k_gemm   <<<gb, 256, 0, stream>>>(bufF, Bhi, Blo, bufH, as1, ad1, pals1, pald1);
  k_agg<__half,false,true><<<nb_wave, 256, 0, stream>>>(bufH, pals1, pald1, rowptr, csrs,
                                         (const __half*)pe, 8, 4, small, 36, b1, h2h);
  k_pool1  <<<256, 256, 0, stream>>>(h2h, sumpool, maxkey);
  k_atts   <<<256, 256, 0, stream>>>(h2h, sumpool, ssum, attraw);
  k_mlp    <<<1, 512, 0, stream>>>(sumpool, maxkey, attraw, ssum,
                                   Wm1, bm1, Wm2, bm2, Wm3, bm3, out);
}

// Round 9
// 472.263 us; speedup vs baseline: 1.2054x; 1.0460x over previous
//
#include <hip/hip_runtime.h>
#include <hip/hip_fp16.h>
#include <type_traits>

static const long long N_ = 50000;
static const long long E_ = 800000;
static const int NCOPY = 8;
#define LOG2E 1.44269504088896f

typedef __attribute__((ext_vector_type(8))) short bf16x8;
typedef __attribute__((ext_vector_type(4))) float f32x4;

__device__ __forceinline__ float lrelu(float x){ return x >= 0.f ? x : 0.2f*x; }
__device__ __forceinline__ unsigned fkey(float x){
  unsigned u = __float_as_uint(x);
  return (u & 0x80000000u) ? ~u : (u | 0x80000000u);
}
__device__ __forceinline__ float unfkey(unsigned k){
  return __uint_as_float((k & 0x80000000u) ? (k & 0x7fffffffu) : ~k);
}
__device__ __forceinline__ unsigned h2u(__half2 h){ return *(unsigned*)&h; }

// ---- fused prologue: deg histogram (+rank) + W1 prep + h0 GEMV (K=5) ----
__global__ void k_pre(const int* __restrict__ ei, int* __restrict__ deg8,
                      unsigned char* __restrict__ rank,
                      const float* __restrict__ W1, ushort* __restrict__ Bhi,
                      ushort* __restrict__ Blo,
                      const float* __restrict__ x, const float* __restrict__ W0,
                      const float* __restrict__ as0, const float* __restrict__ ad0,
                      __half* __restrict__ h0, float* __restrict__ als,
                      float* __restrict__ ald){
  int t = threadIdx.x;
  long long e = (long long)blockIdx.x*256 + t;
  if (e < E_){
    int d = ei[E_ + e];
    int copy = blockIdx.x & (NCOPY-1);
    int old = atomicAdd(&deg8[copy*(int)N_ + d], 1);
    rank[e] = (unsigned char)old;
  }
  if (blockIdx.x < 256){
    int k = blockIdx.x, n = t;
    float v = W1[k*256+n];
    unsigned u = __float_as_uint(v);
    ushort hi = (ushort)(u>>16);
    float rem = v - __uint_as_float(u & 0xffff0000u);
    unsigned ur = __float_as_uint(rem);
    ushort lo = (ushort)((ur + 0x7fff + ((ur>>16)&1)) >> 16);
    int tl = n>>4, kb = k>>5, q = (k>>3)&3, j = k&7;
    long long idx = ((((long long)tl*8+kb)*64 + q*16 + (n&15))<<3) + j;
    Bhi[idx] = hi; Blo[idx] = lo;
  }
  // ---- h0: 16 nodes per block (3125*16 = 50000 exactly) ----
  int w = t>>6, lane = t&63;
  int c = lane*4, head = lane>>4;
  #pragma unroll
  for (int rep=0; rep<4; rep++){
    int wid = blockIdx.x*16 + w*4 + rep;
    if (wid >= (int)N_) break;
    const float* xr = x + wid*5;
    float xv[5];
    #pragma unroll
    for (int f=0; f<5; f++) xv[f] = xr[f];
    float a0=0,a1=0,a2=0,a3=0;
    #pragma unroll
    for (int f=0; f<5; f++){
      const float* wr = W0 + f*256 + c;
      a0 += xv[f]*wr[0]; a1 += xv[f]*wr[1]; a2 += xv[f]*wr[2]; a3 += xv[f]*wr[3];
    }
    uint2 pk = make_uint2(h2u(__floats2half2_rn(a0,a1)), h2u(__floats2half2_rn(a2,a3)));
    *(uint2*)(h0 + (long long)wid*256 + c) = pk;
    const float* asp = as0 + c;
    const float* adp = ad0 + c;
    float ss = a0*asp[0]+a1*asp[1]+a2*asp[2]+a3*asp[3];
    float dd = a0*adp[0]+a1*adp[1]+a2*adp[2]+a3*adp[3];
    #pragma unroll
    for (int m=1; m<16; m<<=1){ ss += __shfl_xor(ss, m); dd += __shfl_xor(dd, m); }
    if ((lane&15)==0){ als[wid*4+head]=ss*LOG2E; ald[wid*4+head]=dd*LOG2E; }
  }
}

// ---- scan phase 1: per-block sums of total deg + ea column partial sums ----
__global__ void k_scan1(const int* __restrict__ deg8, int* __restrict__ bsum,
                        const float* __restrict__ ea, float* __restrict__ eapart){
  __shared__ int lds[256];
  __shared__ float fl[256];
  int t = threadIdx.x;
  long long idx = (long long)blockIdx.x*256 + t;
  int v = 0;
  if (idx < N_){
    #pragma unroll
    for (int c=0;c<NCOPY;c++) v += deg8[c*(int)N_ + idx];
  }
  lds[t] = v;
  float s = 0.f;
  for (long long i = (long long)blockIdx.x*256 + t; i < E_*4; i += (long long)gridDim.x*256)
    s += ea[i];
  fl[t] = s;
  __syncthreads();
  for (int st=128; st>=1; st>>=1){
    if (t<st) lds[t] += lds[t+st];
    if (t<st && st>=4) fl[t] += fl[t+st];
    __syncthreads();
  }
  if (t==0) bsum[blockIdx.x] = lds[0];
  if (t<4) eapart[blockIdx.x*4 + t] = fl[t];
}

// ---- phase 2: scan block sums + fused "small" precompute (log2-scaled) ----
__global__ void k_scan2(const int* __restrict__ bsum, int* __restrict__ bpre, int nb,
                        int* __restrict__ rowptr,
                        const float* __restrict__ We0, const float* __restrict__ ae0,
                        const float* __restrict__ We1, const float* __restrict__ ae1,
                        const float* __restrict__ eapart, float* __restrict__ small){
  __shared__ int lds[256];
  __shared__ float sea[4];
  int t = threadIdx.x;
  int v = (t < nb) ? bsum[t] : 0;
  lds[t] = v; __syncthreads();
  for (int off=1; off<256; off<<=1){
    int add = (t>=off) ? lds[t-off] : 0;
    __syncthreads();
    lds[t] += add;
    __syncthreads();
  }
  if (t < nb) bpre[t] = lds[t] - v;     // exclusive
  if (t == 0) rowptr[N_] = (int)E_;
  if (t < 4){
    float s = 0.f;
    for (int b=0;b<nb;b++) s += eapart[b*4+t];
    sea[t] = s;
  }
  if (t < 32){
    int l = t>>4, f = (t>>2)&3, h = t&3;
    const float* We = l ? We1 : We0;
    const float* ae = l ? ae1 : ae0;
    float s = 0.f;
    for (int cc=0; cc<64; cc++) s += We[f*256 + h*64 + cc]*ae[h*64+cc];
    small[l*16 + f*4 + h] = s * LOG2E;
  }
  __syncthreads();
  if (t < 8){
    int l = t>>2, h = t&3;
    const float* Ae = small + l*16;       // already scaled
    const float invE = 1.f/(float)E_;
    float s = 0.f;
    for (int f=0; f<4; f++) s += sea[f]*invE*Ae[f*4+h];
    small[32 + l*4 + h] = s;
  }
}

// ---- phase 3: local scan + block offset -> rowptr + per-copy bases ----
__global__ void k_scan3(const int* __restrict__ deg8, const int* __restrict__ bpre,
                        int* __restrict__ rowptr, int* __restrict__ base){
  __shared__ int lds[256];
  int t = threadIdx.x;
  long long idx = (long long)blockIdx.x*256 + t;
  int dd[NCOPY]; int v = 0;
  if (idx < N_){
    #pragma unroll
    for (int c=0;c<NCOPY;c++){ dd[c] = deg8[c*(int)N_ + idx]; v += dd[c]; }
  }
  lds[t] = v; __syncthreads();
  for (int off=1; off<256; off<<=1){
    int add = (t>=off) ? lds[t-off] : 0;
    __syncthreads();
    lds[t] += add;
    __syncthreads();
  }
  if (idx < N_){
    int rp = bpre[blockIdx.x] + lds[t] - v;
    rowptr[idx] = rp;
    int cum = rp;
    #pragma unroll
    for (int c=0;c<NCOPY;c++){ base[c*(int)N_ + idx] = cum; cum += dd[c]; }
  }
}

// ---- scatter (atomic-free): pos = base[copy][d] + rank[e]; fused p0 + ale1 ----
__global__ void k_scatter(const int* __restrict__ ei, const float* __restrict__ ea,
                          const int* __restrict__ base, const unsigned char* __restrict__ rank,
                          int* __restrict__ csrs, uint4* __restrict__ pe,
                          const float* __restrict__ small,
                          const float* __restrict__ als0, const float* __restrict__ ald0){
  long long e = (long long)blockIdx.x*256 + threadIdx.x;
  if (e >= E_) return;
  int s = ei[e], d = ei[E_+e];
  int copy = blockIdx.x & (NCOPY-1);
  int pos = base[copy*(int)N_ + d] + (int)rank[e];
  csrs[pos] = s;
  float4 v = *(const float4*)(ea + e*4);
  float4 As = *(const float4*)(als0 + s*4);
  float4 Ad = *(const float4*)(ald0 + d*4);
  float as_[4] = {As.x,As.y,As.z,As.w};
  float ad_[4] = {Ad.x,Ad.y,Ad.z,Ad.w};
  float p0[4], o1[4];
  #pragma unroll
  for (int h=0; h<4; h++){
    float a0 = v.x*small[0+h]  + v.y*small[4+h]  + v.z*small[8+h]  + v.w*small[12+h];
    p0[h] = exp2f(lrelu(as_[h] + ad_[h] + a0));
    o1[h] = v.x*small[16+h] + v.y*small[20+h] + v.z*small[24+h] + v.w*small[28+h];
  }
  uint4 pk = make_uint4(h2u(__floats2half2_rn(p0[0],p0[1])),
                        h2u(__floats2half2_rn(p0[2],p0[3])),
                        h2u(__floats2half2_rn(o1[0],o1[1])),
                        h2u(__floats2half2_rn(o1[2],o1[3])));
  pe[pos] = pk;
}

// ---- GAT aggregation: one wave/node; 2 edges/wave (16B/lane), 4-pair unroll.
// UN=4 keeps VGPR ~32 -> 8 waves/SIMD; UN=6 (R7) cost occupancy 68->42% and
// regressed 64->77us. INLINE_P computes layer-1 p in-loop (no palpha1 pass).
template<typename OutT, bool RELU, bool INLINE_P>
__global__ __launch_bounds__(256) void k_agg(const __half* __restrict__ hin,
    const float* __restrict__ als, const float* __restrict__ ald,
    const int* __restrict__ rowptr, const int* __restrict__ csrs,
    const __half* __restrict__ ph, int pstride, int poff,
    const float* __restrict__ small, int loop_off,
    const float* __restrict__ bias, OutT* __restrict__ out){
  int wid = (int)(((long long)blockIdx.x*256 + threadIdx.x) >> 6);
  int lane = threadIdx.x & 63;
  if (wid >= (int)N_) return;
  int half_ = lane>>5, l5 = lane&31;
  int head = l5>>3, c8 = l5*8;
  const uint4* hp = (const uint4*)hin;
  float aldv = ald[wid*4+head];
  float a[8]; float den;
  // self-loop (lower half only; upper half starts empty)
  {
    float pS = exp2f(lrelu(als[wid*4+head] + aldv + small[loop_off+head]));
    float pp = (half_==0) ? pS : 0.f;
    uint4 r = hp[wid*32 + l5];
    float2 f0 = __half22float2(*(__half2*)&r.x);
    float2 f1 = __half22float2(*(__half2*)&r.y);
    float2 f2 = __half22float2(*(__half2*)&r.z);
    float2 f3 = __half22float2(*(__half2*)&r.w);
    den = pp;
    a[0]=pp*f0.x; a[1]=pp*f0.y; a[2]=pp*f1.x; a[3]=pp*f1.y;
    a[4]=pp*f2.x; a[5]=pp*f2.y; a[6]=pp*f3.x; a[7]=pp*f3.y;
  }
  int beg = rowptr[wid], end = rowptr[wid+1];
  int i = beg;
  const int UN = 4;
  for (; i + 2*UN-1 < end; i += 2*UN){
    int sv[UN]; float pv[UN]; uint4 rr[UN];
    #pragma unroll
    for (int k=0;k<UN;k++) sv[k] = csrs[i + 2*k + half_];
    #pragma unroll
    for (int k=0;k<UN;k++) rr[k] = hp[sv[k]*32 + l5];     // big gathers first
    #pragma unroll
    for (int k=0;k<UN;k++){
      int e = i + 2*k + half_;
      if (INLINE_P){
        float alev = __half2float(ph[e*pstride + poff + head]);
        float alsv = als[sv[k]*4 + head];
        pv[k] = exp2f(lrelu(alsv + aldv + alev));
      } else {
        pv[k] = __half2float(ph[e*pstride + poff + head]);
      }
    }
    #pragma unroll
    for (int k=0;k<UN;k++){
      float2 f0 = __half22float2(*(__half2*)&rr[k].x);
      float2 f1 = __half22float2(*(__half2*)&rr[k].y);
      float2 f2 = __half22float2(*(__half2*)&rr[k].z);
      float2 f3 = __half22float2(*(__half2*)&rr[k].w);
      float p = pv[k];
      den += p;
      a[0]+=p*f0.x; a[1]+=p*f0.y; a[2]+=p*f1.x; a[3]+=p*f1.y;
      a[4]+=p*f2.x; a[5]+=p*f2.y; a[6]+=p*f3.x; a[7]+=p*f3.y;
    }
  }
  for (; i < end; i += 2){
    int e = i + half_;
    bool act = (e < end);
    int ee = act ? e : (end-1);
    int s0 = csrs[ee];
    float p;
    if (INLINE_P){
      float alev = __half2float(ph[ee*pstride + poff + head]);
      float alsv = als[s0*4 + head];
      p = exp2f(lrelu(alsv + aldv + alev));
    } else {
      p = __half2float(ph[ee*pstride + poff + head]);
    }
    if (!act) p = 0.f;
    uint4 r = hp[s0*32 + l5];
    float2 f0 = __half22float2(*(__half2*)&r.x);
    float2 f1 = __half22float2(*(__half2*)&r.y);
    float2 f2 = __half22float2(*(__half2*)&r.z);
    float2 f3 = __half22float2(*(__half2*)&r.w);
    den += p;
    a[0]+=p*f0.x; a[1]+=p*f0.y; a[2]+=p*f1.x; a[3]+=p*f1.y;
    a[4]+=p*f2.x; a[5]+=p*f2.y; a[6]+=p*f3.x; a[7]+=p*f3.y;
  }
  // merge halves
  den += __shfl_xor(den, 32);
  #pragma unroll
  for (int j=0;j<8;j++) a[j] += __shfl_xor(a[j], 32);
  if (half_ == 0){
    float inv = 1.f/(den + 1e-16f);
    float4 b0 = *(const float4*)(bias + c8);
    float4 b1 = *(const float4*)(bias + c8 + 4);
    float o[8];
    o[0]=a[0]*inv+b0.x; o[1]=a[1]*inv+b0.y; o[2]=a[2]*inv+b0.z; o[3]=a[3]*inv+b0.w;
    o[4]=a[4]*inv+b1.x; o[5]=a[5]*inv+b1.y; o[6]=a[6]*inv+b1.z; o[7]=a[7]*inv+b1.w;
    if (RELU){
      #pragma unroll
      for (int j=0;j<8;j++) o[j] = fmaxf(o[j], 0.f);
    }
    if constexpr (std::is_same<OutT,__half>::value){
      uint4 qk = make_uint4(h2u(__floats2half2_rn(o[0],o[1])), h2u(__floats2half2_rn(o[2],o[3])),
                            h2u(__floats2half2_rn(o[4],o[5])), h2u(__floats2half2_rn(o[6],o[7])));
      *(uint4*)(out + (long long)wid*256 + c8) = qk;
    } else {
      *(float4*)(out + (long long)wid*256 + c8)     = make_float4(o[0],o[1],o[2],o[3]);
      *(float4*)(out + (long long)wid*256 + c8 + 4) = make_float4(o[4],o[5],o[6],o[7]);
    }
  }
}

// ---- h1 = x1 @ W1 via split-bf16 MFMA (3 products); fp16 out; fused als1/ald1 ----
__global__ __launch_bounds__(256) void k_gemm(const float* __restrict__ A,
    const ushort* __restrict__ Bhi, const ushort* __restrict__ Blo,
    __half* __restrict__ Ch, const float* __restrict__ as1, const float* __restrict__ ad1,
    float* __restrict__ als, float* __restrict__ ald){
  __shared__ ushort Ah[32*264];
  __shared__ ushort Al[32*264];
  int t = threadIdx.x;
  long long base = (long long)blockIdx.x*32;
  for (int i=t; i<2048; i+=256){
    int r = i>>6, q4 = i&63;
    float4 v = make_float4(0.f,0.f,0.f,0.f);
    if (base + r < N_) v = *(const float4*)(A + (base+r)*256 + q4*4);
    float vv[4] = {v.x,v.y,v.z,v.w};
    ushort hh[4], ll[4];
    #pragma unroll
    for (int e=0;e<4;e++){
      unsigned u = __float_as_uint(vv[e]);
      hh[e] = (ushort)(u>>16);
      float rem = vv[e] - __uint_as_float(u & 0xffff0000u);
      unsigned ur = __float_as_uint(rem);
      ll[e] = (ushort)((ur + 0x7fff + ((ur>>16)&1)) >> 16);
    }
    int off = r*264 + q4*4;
    *(ushort4*)(Ah+off) = make_ushort4(hh[0],hh[1],hh[2],hh[3]);
    *(ushort4*)(Al+off) = make_ushort4(ll[0],ll[1],ll[2],ll[3]);
  }
  __syncthreads();
  int w = t>>6, lane = t&63, m = lane&15, q = lane>>4;
  int rbase = (w>>1)*16;
  int nhalf = (w&1)*8;
  f32x4 acc[8];
  #pragma unroll
  for (int i=0;i<8;i++) acc[i] = (f32x4){0.f,0.f,0.f,0.f};
  for (int kb=0; kb<8; kb++){
    int aoff = (rbase+m)*264 + kb*32 + q*8;
    bf16x8 ah = *(const bf16x8*)(Ah + aoff);
    bf16x8 al = *(const bf16x8*)(Al + aoff);
    #pragma unroll
    for (int tt=0; tt<8; tt++){
      long long bidx = ((((long long)(nhalf+tt)*8+kb)*64 + lane)<<3);
      bf16x8 bh = *(const bf16x8*)(Bhi + bidx);
      bf16x8 bl = *(const bf16x8*)(Blo + bidx);
      acc[tt] = __builtin_amdgcn_mfma_f32_16x16x32_bf16(ah, bh, acc[tt], 0,0,0);
      acc[tt] = __builtin_amdgcn_mfma_f32_16x16x32_bf16(al, bh, acc[tt], 0,0,0);
      acc[tt] = __builtin_amdgcn_mfma_f32_16x16x32_bf16(ah, bl, acc[tt], 0,0,0);
    }
  }
  float ssv[4][2], ddv[4][2];
  #pragma unroll
  for (int r=0;r<4;r++){ ssv[r][0]=0.f; ssv[r][1]=0.f; ddv[r][0]=0.f; ddv[r][1]=0.f; }
  #pragma unroll
  for (int tt=0; tt<8; tt++){
    int col = (nhalf+tt)*16 + m;
    float as_ = as1[col], ad_ = ad1[col];
    int hh = tt>>2;
    #pragma unroll
    for (int r=0;r<4;r++){
      ssv[r][hh] += acc[tt][r]*as_;
      ddv[r][hh] += acc[tt][r]*ad_;
    }
  }
  #pragma unroll
  for (int r=0;r<4;r++){
    #pragma unroll
    for (int hh=0; hh<2; hh++){
      #pragma unroll
      for (int mm=1; mm<16; mm<<=1){
        ssv[r][hh] += __shfl_xor(ssv[r][hh], mm);
        ddv[r][hh] += __shfl_xor(ddv[r][hh], mm);
      }
    }
  }
  #pragma unroll
  for (int r=0;r<4;r++){
    long long grow = base + rbase + q*4 + r;
    if (grow < N_){
      #pragma unroll
      for (int tt=0; tt<8; tt++)
        Ch[grow*256 + (nhalf+tt)*16 + m] = __float2half(acc[tt][r]);
      if (m==0){
        int hb = (w&1)*2;
        als[grow*4 + hb+0] = ssv[r][0]*LOG2E;
        ald[grow*4 + hb+0] = ddv[r][0]*LOG2E;
        als[grow*4 + hb+1] = ssv[r][1]*LOG2E;
        ald[grow*4 + hb+1] = ddv[r][1]*LOG2E;
      }
    }
  }
}

// ---- column-wise sum & max over nodes (fp16 h2) ----
__global__ void k_pool1(const __half* __restrict__ h2, float* __restrict__ sum_pool,
                        unsigned* __restrict__ maxkey){
  int c = threadIdx.x; // 256
  float s = 0.f; float m = -3.4e38f;
  for (long long n = blockIdx.x; n < N_; n += gridDim.x){
    float v = __half2float(h2[n*256+c]); s += v; m = fmaxf(m, v);
  }
  atomicAdd(&sum_pool[c], s);
  atomicMax(&maxkey[c], fkey(m));
}

// ---- fused attention pool: s[n]=dot(h2[n],mp); accumulate ssum & att_raw ----
__global__ void k_atts(const __half* __restrict__ h2, const float* __restrict__ sum_pool,
                       float* __restrict__ ssum, float* __restrict__ att_raw){
  __shared__ float part[4][256];
  __shared__ float es[4];
  int t = threadIdx.x; int lane = t&63; int w = t>>6;
  const float invN = 1.f/(float)N_;
  int c = lane*4;
  float4 mp = *(const float4*)(sum_pool + c);
  float esum = 0.f;
  float acc0=0.f, acc1=0.f, acc2=0.f, acc3=0.f;
  for (long long wid = (long long)blockIdx.x*4 + w; wid < N_; wid += (long long)gridDim.x*4){
    uint2 pk = *(const uint2*)(h2 + wid*256 + c);
    float2 a01 = __half22float2(*(__half2*)&pk.x);
    float2 a23 = __half22float2(*(__half2*)&pk.y);
    float s = (a01.x*mp.x + a01.y*mp.y + a23.x*mp.z + a23.y*mp.w)*invN;
    #pragma unroll
    for (int m=1; m<64; m<<=1) s += __shfl_xor(s, m);
    float e = __expf(s);
    if (lane==0) esum += e;
    acc0 += e*a01.x; acc1 += e*a01.y; acc2 += e*a23.x; acc3 += e*a23.y;
  }
  part[w][c+0]=acc0; part[w][c+1]=acc1; part[w][c+2]=acc2; part[w][c+3]=acc3;
  if (lane==0) es[w] = esum;
  __syncthreads();
  if (t < 256){
    float v = part[0][t]+part[1][t]+part[2][t]+part[3][t];
    atomicAdd(&att_raw[t], v);
  }
  if (t==0) atomicAdd(ssum, es[0]+es[1]+es[2]+es[3]);
}

// ---- final MLP: [768] -> 128 -> 64 -> 128, split-K across 512 threads ----
__global__ void k_mlp(const float* __restrict__ sum_pool, const unsigned* __restrict__ maxkey,
                      const float* __restrict__ att_raw, const float* __restrict__ ssum,
                      const float* __restrict__ Wm1, const float* __restrict__ bm1,
                      const float* __restrict__ Wm2, const float* __restrict__ bm2,
                      const float* __restrict__ Wm3, const float* __restrict__ bm3,
                      float* __restrict__ out){
  __shared__ float comb[768];
  __shared__ float z1p[4][128]; __shared__ float z1[128];
  __shared__ float z2p[8][64];  __shared__ float z2[64];
  __shared__ float z3p[4][128];
  int t = threadIdx.x; // 512
  const float invN = 1.f/(float)N_;
  float invS = 1.f/(*ssum);
  for (int i=t; i<768; i+=512){
    float v;
    if (i < 256)      v = sum_pool[i]*invN;
    else if (i < 512) v = unfkey(maxkey[i-256]);
    else              v = att_raw[i-512]*invS;
    comb[i] = v;
  }
  __syncthreads();
  { int n = t&127, part = t>>7;
    float a = 0.f;
    for (int f=part*192; f<part*192+192; f++) a += comb[f]*Wm1[f*128+n];
    z1p[part][n] = a;
  }
  __syncthreads();
  if (t < 128)
    z1[t] = fmaxf(bm1[t] + z1p[0][t]+z1p[1][t]+z1p[2][t]+z1p[3][t], 0.f);
  __syncthreads();
  { int n = t&63, part = t>>6;
    float a = 0.f;
    for (int f=part*16; f<part*16+16; f++) a += z1[f]*Wm2[f*64+n];
    z2p[part][n] = a;
  }
  __syncthreads();
  if (t < 64){
    float a = bm2[t];
    #pragma unroll
    for (int p=0;p<8;p++) a += z2p[p][t];
    z2[t] = fmaxf(a, 0.f);
  }
  __syncthreads();
  { int n = t&127, part = t>>7;
    float a = 0.f;
    for (int f=part*16; f<part*16+16; f++) a += z2[f]*Wm3[f*128+n];
    z3p[part][n] = a;
  }
  __syncthreads();
  if (t < 128)
    out[t] = bm3[t] + z3p[0][t]+z3p[1][t]+z3p[2][t]+z3p[3][t];
}

extern "C" void kernel_launch(void* const* d_in, const int* in_sizes, int n_in,
                              void* d_out, int out_size, void* d_ws, size_t ws_size,
                              hipStream_t stream){
  (void)in_sizes; (void)n_in; (void)out_size; (void)ws_size;
  const float* x   = (const float*)d_in[0];
  const int*   ei  = (const int*)d_in[1];
  const float* ea  = (const float*)d_in[2];
  const float* W0  = (const float*)d_in[3];
  const float* as0 = (const float*)d_in[4];
  const float* ad0 = (const float*)d_in[5];
  const float* We0 = (const float*)d_in[6];
  const float* ae0 = (const float*)d_in[7];
  const float* b0  = (const float*)d_in[8];
  const float* W1  = (const float*)d_in[9];
  const float* as1 = (const float*)d_in[10];
  const float* ad1 = (const float*)d_in[11];
  const float* We1 = (const float*)d_in[12];
  const float* ae1 = (const float*)d_in[13];
  const float* b1  = (const float*)d_in[14];
  const float* Wm1 = (const float*)d_in[15];
  const float* bm1 = (const float*)d_in[16];
  const float* Wm2 = (const float*)d_in[17];
  const float* bm2 = (const float*)d_in[18];
  const float* Wm3 = (const float*)d_in[19];
  const float* bm3 = (const float*)d_in[20];
  float* out = (float*)d_out;

  char* ws = (char*)d_ws;
  size_t o = 0;
  auto alloc = [&](size_t bytes)->size_t{
    size_t r = o; o = (o + bytes + 255) & ~(size_t)255; return r;
  };
  size_t o_bufF   = alloc((size_t)N_*256*4);   // x1 (fp32), then h2 (fp16)
  size_t o_bufH   = alloc((size_t)N_*256*2);   // h0, then h1 (fp16)
  size_t o_als0   = alloc((size_t)N_*4*4);
  size_t o_ald0   = alloc((size_t)N_*4*4);
  size_t o_als1   = alloc((size_t)N_*4*4);
  size_t o_ald1   = alloc((size_t)N_*4*4);
  size_t o_rowptr = alloc((size_t)(N_+1)*4);
  size_t o_csrs   = alloc((size_t)E_*4);       // src only
  size_t o_pe     = alloc((size_t)E_*16);      // uint4: p0 x4 fp16 | ale1 x4 fp16
  size_t o_rank   = alloc((size_t)E_);         // uchar rank within (copy,dst)
  size_t o_base   = alloc((size_t)NCOPY*N_*4); // per-copy CSR bases
  size_t o_Bhi    = alloc((size_t)256*256*2);
  size_t o_Blo    = alloc((size_t)256*256*2);
  size_t o_bsum   = alloc(256*4);
  size_t o_bpre   = alloc(256*4);
  size_t o_eapart = alloc(256*4*4);
  // --- zero block ---
  size_t zstart   = o;
  size_t o_deg8   = alloc((size_t)NCOPY*N_*4);
  size_t o_sumpool= alloc(256*4);
  size_t o_maxkey = alloc(256*4);
  size_t o_attraw = alloc(256*4);
  size_t o_ssum   = alloc(4);
  size_t zend     = o;
  size_t o_small  = alloc(40*4);

  float*  bufF   = (float*)(ws + o_bufF);
  __half* bufH   = (__half*)(ws + o_bufH);
  __half* h2h    = (__half*)(ws + o_bufF);     // reuse bufF region for fp16 h2
  float* pals0  = (float*)(ws + o_als0);
  float* pald0  = (float*)(ws + o_ald0);
  float* pals1  = (float*)(ws + o_als1);
  float* pald1  = (float*)(ws + o_ald1);
  int*   rowptr = (int*)(ws + o_rowptr);
  int*   csrs   = (int*)(ws + o_csrs);
  uint4* pe     = (uint4*)(ws + o_pe);
  unsigned char* rank = (unsigned char*)(ws + o_rank);
  int*   base   = (int*)(ws + o_base);
  ushort* Bhi   = (ushort*)(ws + o_Bhi);
  ushort* Blo   = (ushort*)(ws + o_Blo);
  int*   bsum   = (int*)(ws + o_bsum);
  int*   bpre   = (int*)(ws + o_bpre);
  float* eapart = (float*)(ws + o_eapart);
  int*   deg8   = (int*)(ws + o_deg8);
  float* sumpool= (float*)(ws + o_sumpool);
  unsigned* maxkey = (unsigned*)(ws + o_maxkey);
  float* attraw = (float*)(ws + o_attraw);
  float* ssum   = (float*)(ws + o_ssum);
  float* small  = (float*)(ws + o_small);

  hipMemsetAsync(ws + zstart, 0, zend - zstart, stream);

  int eb = (int)((E_ + 255)/256);          // 3125
  int nb_wave = (int)((N_*64 + 255)/256);  // 12500 (one wave per node)
  int gb = (int)((N_ + 31)/32);            // 1563 gemm blocks
  int sb = (int)((N_ + 255)/256);          // 196 scan blocks

  k_pre    <<<eb, 256, 0, stream>>>(ei, deg8, rank, W1, Bhi, Blo,
                                    x, W0, as0, ad0, bufH, pals0, pald0);
  k_scan1  <<<sb, 256, 0, stream>>>(deg8, bsum, ea, eapart);
  k_scan2  <<<1, 256, 0, stream>>>(bsum, bpre, sb, rowptr,
                                   We0, ae0, We1, ae1, eapart, small);
  k_scan3  <<<sb, 256, 0, stream>>>(deg8, bpre, rowptr, base);
  k_scatter<<<eb, 256, 0, stream>>>(ei, ea, base, rank, csrs, pe,
                                    small, pals0, pald0);
  k_agg<float,true,false> <<<nb_wave, 256, 0, stream>>>(bufH, pals0, pald0, rowptr, csrs,
                                         (const __half*)pe, 8, 0, small, 32, b0, bufF);
  k_gemm   <<<gb, 256, 0, stream>>>(bufF, Bhi, Blo, bufH, as1, ad1, pals1, pald1);
  k_agg<__half,false,true><<<nb_wave, 256, 0, stream>>>(bufH, pals1, pald1, rowptr, csrs,
                                         (const __half*)pe, 8, 4, small, 36, b1, h2h);
  k_pool1  <<<256, 256, 0, stream>>>(h2h, sumpool, maxkey);
  k_atts   <<<256, 256, 0, stream>>>(h2h, sumpool, ssum, attraw);
  k_mlp    <<<1, 512, 0, stream>>>(sumpool, maxkey, attraw, ssum,
                                   Wm1, bm1, Wm2, bm2, Wm3, bm3, out);
}